// Round 2
// baseline (423.061 us; speedup 1.0000x reference)
//
#include <hip/hip_runtime.h>
#include <cstdint>

#define AS1 __attribute__((address_space(1)))
#define AS3 __attribute__((address_space(3)))

typedef _Float16 half8 __attribute__((ext_vector_type(8)));
typedef _Float16 half4_t __attribute__((ext_vector_type(4)));
typedef float v4f __attribute__((ext_vector_type(4)));

__device__ __forceinline__ void async_ld16(const void* g, void* l) {
  __builtin_amdgcn_global_load_lds((const AS1 uint32_t*)g, (AS3 uint32_t*)l, 16, 0, 0);
}

// T5 relative-position bucket for delta = k - q (bidirectional, 32 buckets, max_dist 128).
// Exact-boundary cases (n = 8,16,32,64) in integer arithmetic; n>=91 clamps; float path
// has >=0.015 margin in value space vs ~1e-6 fp32 error.
__device__ __forceinline__ int t5_bucket(int delta) {
  int n = -delta;  // n = q - k
  int ret = 0;
  if (n < 0) { ret = 16; n = -n; }
  if (n < 8) return n + ret;
  if (n >= 91) return 15 + ret;
  if ((n & (n - 1)) == 0) {
    int l = 31 - __clz(n);
    int v = 2 + 2 * l;
    return (v > 15 ? 15 : v) + ret;
  }
  int v = 8 + (int)(logf((float)n * 0.125f) * (8.0f / logf(16.0f)));
  return (v > 15 ? 15 : v) + ret;
}

// ---------------- prep: hs fp32->fp16 (x<4096) + 4 weight transposes (x>=4096) --------
__global__ void k_prep(const float* __restrict__ hs, const float* __restrict__ Wq,
                       const float* __restrict__ Wk, const float* __restrict__ Wv,
                       const float* __restrict__ Wo, _Float16* __restrict__ hsF,
                       _Float16* __restrict__ wqkvT, _Float16* __restrict__ woT) {
  const int tid = threadIdx.x;
  if (blockIdx.x < 4096) {
    int t = blockIdx.x * 256 + tid;
    float4 f = ((const float4*)hs)[t];
    half4_t h = {(_Float16)f.x, (_Float16)f.y, (_Float16)f.z, (_Float16)f.w};
    ((half4_t*)hsF)[t] = h;
    return;
  }
  __shared__ float tile[32][33];
  const int idx = blockIdx.x - 4096;
  const int z = idx >> 10, rem = idx & 1023;
  const float* src = (z == 0) ? Wq : (z == 1) ? Wk : (z == 2) ? Wv : Wo;
  _Float16* dst = (z < 3) ? (wqkvT + ((size_t)z << 20)) : woT;
  const int tx = tid & 31, ty = tid >> 5;
  const int bx = (rem & 31) * 32, by = (rem >> 5) * 32;
#pragma unroll
  for (int i = 0; i < 32; i += 8)
    tile[ty + i][tx] = src[(size_t)(by + ty + i) * 1024 + bx + tx];
  __syncthreads();
#pragma unroll
  for (int i = 0; i < 32; i += 8)
    dst[(size_t)(bx + ty + i) * 1024 + by + tx] = (_Float16)tile[tx][ty + i];
}

// ---------------- QKV GEMM fused with position-bias writer (EVEN 64-col chunks) -------
// 128x128 tile, BK=32, grid (24,32) = 768 blocks = exactly 3/CU (launch_bounds 3):
// one clean residency round, 3 waves/SIMD. Counted-vmcnt barrier (T4): the 4
// global_load_lds are issued first, then the 2 bias stores; barrier 2 waits vmcnt(2)
// so staging is complete but the stores stay in flight across the barrier -- the
// store-drain stall that vmcnt(0) forced every iteration is gone. Barrier 1 needs only
// lgkmcnt(0) (all ds_reads were consumed by MFMAs before it).
__global__ __launch_bounds__(256, 3) void k_gemm_qkv_bias(
    const _Float16* __restrict__ A, const _Float16* __restrict__ BT,
    _Float16* __restrict__ qkv, _Float16* __restrict__ vT,
    const float* __restrict__ rel, float* __restrict__ outb) {
  __shared__ __align__(16) _Float16 As[128 * 32];
  __shared__ __align__(16) _Float16 Bs[128 * 32];
  __shared__ float btab[256];  // bias vs delta in [-128,127] (mixed band only)
  const int tid = threadIdx.x;
  const int wave = tid >> 6, lane = tid & 63;
  const int l15 = lane & 15, quad = lane >> 4;
  const int m0 = blockIdx.y * 128, n0 = blockIdx.x * 128;
  const int wm = (wave >> 1) * 64, wn = (wave & 1) * 64;
  const int r0 = tid >> 2, c0 = (tid & 3) * 8;
  constexpr int K = 1024;

  const int bid = blockIdx.y * 24 + blockIdx.x;  // 0..767
  const bool do_bias = bid < 512;
  const int hB = bid >> 5;           // head for this block's bias slice
  const int qoff = (bid & 31) * 64;  // 64-q strip within the head
  float c_past = 0.f, c_fut = 0.f;
  if (do_bias) {
    btab[tid & 255] = rel[t5_bucket((tid & 255) - 128) * 16 + hB];
    c_past = rel[15 * 16 + hB];
    c_fut = rel[31 * 16 + hB];
  }

  v4f acc[4][4] = {};
  for (int k0 = 0; k0 < K; k0 += 32) {
    // barrier 1: all waves done READING As/Bs (their ds_reads retired before their
    // MFMAs issued); no vmcnt wait -- older bias stores keep draining in background.
    asm volatile("s_waitcnt lgkmcnt(0)\ns_barrier" ::: "memory");
    async_ld16(A + (size_t)(m0 + r0) * K + k0 + c0, (char*)As + (size_t)(wave * 64) * 16);
    async_ld16(A + (size_t)(m0 + 64 + r0) * K + k0 + c0,
               (char*)As + (size_t)(256 + wave * 64) * 16);
    async_ld16(BT + (size_t)(n0 + r0) * K + k0 + c0, (char*)Bs + (size_t)(wave * 64) * 16);
    async_ld16(BT + (size_t)(n0 + 64 + r0) * K + k0 + c0,
               (char*)Bs + (size_t)(256 + wave * 64) * 16);

    if (do_bias) {
      // keep the staging loads OLDER than the stores in the vmcnt queue
      __builtin_amdgcn_sched_barrier(0);
      // ---- bias strip (even 64-col chunks): 512 float4 (8 KB) per iter, coalesced ----
      const int iter = k0 >> 5;  // 0..31
#pragma unroll
      for (int j = 0; j < 2; ++j) {
        int fi = iter * 512 + j * 256 + tid;       // 0..16383 within this block's slice
        int qr = qoff + (fi >> 8);                 // q row (2 rows per iter)
        int c = fi & 255;                          // float4 col in even-chunk space
        int k4 = ((c >> 4) << 5) + (c & 15);       // float4 col in full 512-wide row
        int kb = k4 << 2;                          // k element
        float4 v;
        if (kb - qr >= 91) {
          v = make_float4(c_fut, c_fut, c_fut, c_fut);
        } else if (qr - kb - 3 >= 91) {
          v = make_float4(c_past, c_past, c_past, c_past);
        } else {
          v.x = btab[kb + 0 - qr + 128];
          v.y = btab[kb + 1 - qr + 128];
          v.z = btab[kb + 2 - qr + 128];
          v.w = btab[kb + 3 - qr + 128];
        }
        ((float4*)outb)[((size_t)hB * 2048 + qr) * 512 + k4] = v;
      }
      // barrier 2: queue = [ld x4 (oldest), st x2 (newest)]; in-order retirement:
      // vmcnt(2) => all 4 staging loads complete, 2 stores stay in flight.
      asm volatile("s_waitcnt vmcnt(2) lgkmcnt(0)\ns_barrier" ::: "memory");
    } else {
      asm volatile("s_waitcnt vmcnt(0) lgkmcnt(0)\ns_barrier" ::: "memory");
    }

    half8 af[4], bf[4];
#pragma unroll
    for (int mt = 0; mt < 4; ++mt)
      af[mt] = *(const half8*)(As + (wm + mt * 16 + l15) * 32 + quad * 8);
#pragma unroll
    for (int nt = 0; nt < 4; ++nt)
      bf[nt] = *(const half8*)(Bs + (wn + nt * 16 + l15) * 32 + quad * 8);
#pragma unroll
    for (int mt = 0; mt < 4; ++mt)
#pragma unroll
      for (int nt = 0; nt < 4; ++nt)
        acc[mt][nt] = __builtin_amdgcn_mfma_f32_16x16x32_f16(af[mt], bf[nt], acc[mt][nt], 0, 0, 0);
  }
  if (n0 >= 2048) {
    // V block: write vT[((b*16+h)*64+d)][s], 4 consecutive s per lane -> b64 stores
#pragma unroll
    for (int mt = 0; mt < 4; ++mt)
#pragma unroll
      for (int nt = 0; nt < 4; ++nt) {
        int col = n0 + wn + nt * 16 + l15 - 2048;  // h*64 + d
        int row0 = m0 + wm + mt * 16 + quad * 4;   // token
        int bb = row0 >> 11, s0 = row0 & 2047;
        half4_t hv = {(_Float16)acc[mt][nt][0], (_Float16)acc[mt][nt][1],
                      (_Float16)acc[mt][nt][2], (_Float16)acc[mt][nt][3]};
        *(half4_t*)(vT + ((size_t)bb * 1024 + col) * 2048 + s0) = hv;
      }
    return;
  }
#pragma unroll
  for (int mt = 0; mt < 4; ++mt)
#pragma unroll
    for (int nt = 0; nt < 4; ++nt)
#pragma unroll
      for (int r = 0; r < 4; ++r)
        qkv[(size_t)(m0 + wm + mt * 16 + quad * 4 + r) * 3072 + n0 + wn + nt * 16 + l15] =
            (_Float16)acc[mt][nt][r];
}

// ---------------- output projection GEMM: 128x64 tile ----------------
__global__ __launch_bounds__(256, 2) void k_gemm_n64(const _Float16* __restrict__ A,
                                                     const _Float16* __restrict__ BT,
                                                     float* __restrict__ C, int K, int ldc) {
  __shared__ __align__(16) _Float16 As[128 * 32];
  __shared__ __align__(16) _Float16 Bs[64 * 32];
  const int tid = threadIdx.x;
  const int wave = tid >> 6, lane = tid & 63;
  const int l15 = lane & 15, quad = lane >> 4;
  const int m0 = blockIdx.y * 128, n0 = blockIdx.x * 64;
  const int wm = (wave >> 1) * 64, wn = (wave & 1) * 32;
  const int r0 = tid >> 2, c0 = (tid & 3) * 8;
  v4f acc[4][2] = {};
  for (int k0 = 0; k0 < K; k0 += 32) {
    asm volatile("s_waitcnt lgkmcnt(0)\ns_barrier" ::: "memory");
    async_ld16(A + (size_t)(m0 + r0) * K + k0 + c0, (char*)As + (size_t)(wave * 64) * 16);
    async_ld16(A + (size_t)(m0 + 64 + r0) * K + k0 + c0,
               (char*)As + (size_t)(256 + wave * 64) * 16);
    async_ld16(BT + (size_t)(n0 + r0) * K + k0 + c0, (char*)Bs + (size_t)(wave * 64) * 16);
    asm volatile("s_waitcnt vmcnt(0) lgkmcnt(0)\ns_barrier" ::: "memory");
    half8 af[4], bf[2];
#pragma unroll
    for (int mt = 0; mt < 4; ++mt)
      af[mt] = *(const half8*)(As + (wm + mt * 16 + l15) * 32 + quad * 8);
#pragma unroll
    for (int nt = 0; nt < 2; ++nt)
      bf[nt] = *(const half8*)(Bs + (wn + nt * 16 + l15) * 32 + quad * 8);
#pragma unroll
    for (int mt = 0; mt < 4; ++mt)
#pragma unroll
      for (int nt = 0; nt < 2; ++nt)
        acc[mt][nt] = __builtin_amdgcn_mfma_f32_16x16x32_f16(af[mt], bf[nt], acc[mt][nt], 0, 0, 0);
  }
#pragma unroll
  for (int mt = 0; mt < 4; ++mt)
#pragma unroll
    for (int nt = 0; nt < 2; ++nt)
#pragma unroll
      for (int r = 0; r < 4; ++r)
        C[(size_t)(m0 + wm + mt * 16 + quad * 4 + r) * ldc + n0 + wn + nt * 16 + l15] =
            acc[mt][nt][r];
}

// ---------------- fused flash attention, double-buffered K/V, 1 barrier/iter ----------
// grid (16,16,2) = 512 blocks (2/CU), 4 waves, wave owns 32 q (qt=2).
// Pipeline: prefetch tile i+1 globals during compute of tile i; stage into buf^1 after
// compute (no reader conflict); single end-of-iter barrier (lgkm-only: bias stores and
// already-consumed prefetch loads are NOT drained at the barrier). P round-trip stays
// barrier-free (each wave reads only its own P rows). This kernel also streams the ODD
// 64-col chunks of the position-bias output. Exact defer-max: skip the alpha-rescale
// when no lane's running max grows (alpha == 1 exactly).
__global__ __launch_bounds__(256, 2) void k_attn(const _Float16* __restrict__ qkv,
                                                 const _Float16* __restrict__ vT,
                                                 const float* __restrict__ mask,
                                                 const float* __restrict__ rel,
                                                 _Float16* __restrict__ ctx,
                                                 float* __restrict__ outb) {
  constexpr int S = 2048, LD = 3072;
  __shared__ __align__(16) _Float16 Ks[2][64 * 72];  // [buf][kv][d] pad->LD 72
  __shared__ __align__(16) _Float16 VT[2][64 * 72];  // [buf][d][kv]
  __shared__ __align__(16) _Float16 Psh[128 * 72];   // [q][kv] per-wave-owned rows
  __shared__ float btab[512];                        // bias vs delta in [-256,255]
  const int tid = threadIdx.x, wave = tid >> 6, lane = tid & 63;
  const int l15 = lane & 15, quad = lane >> 4;
  const int q0 = blockIdx.x * 128, h = blockIdx.y, b = blockIdx.z;

  for (int j = tid; j < 512; j += 256) btab[j] = rel[t5_bucket(j - 256) * 16 + h];
  const float c_past = rel[15 * 16 + h];  // q - k >= 91
  const float c_fut = rel[31 * 16 + h];   // k - q >= 91

  half8 bq[2][2];
#pragma unroll
  for (int qt = 0; qt < 2; ++qt) {
    const _Float16* qp = qkv + (size_t)(b * S + q0 + wave * 32 + qt * 16 + l15) * LD + h * 64;
    bq[qt][0] = *(const half8*)(qp + quad * 8);
    bq[qt][1] = *(const half8*)(qp + 32 + quad * 8);
  }
  v4f o[2][4] = {};
  float mrun[2] = {-INFINITY, -INFINITY};
  float lrun[2] = {0.f, 0.f};

  const int srow = tid >> 2, scol = (tid & 3) * 8;
  const _Float16* kg = qkv + (size_t)(b * S + srow) * LD + 1024 + h * 64 + scol;
  const _Float16* vg = vT + ((size_t)((b * 16 + h) * 64 + srow)) * S + scol;
  const float4* mkp = (const float4*)(mask + (size_t)b * S);

  // bias-writer constants: this block owns q-rows [qrow0, qrow0+64) of head h
  const int qrow0 = q0 + b * 64;
  float4* const bias_base = (float4*)outb + ((size_t)h * 2048 + qrow0) * 512;

  // stage tile 0 into buf 0
  {
    half8 kr0 = *(const half8*)(kg);
    half8 kr1 = *(const half8*)(kg + 32);
    half8 vr0 = *(const half8*)(vg);
    half8 vr1 = *(const half8*)(vg + 32);
    *(half8*)(&Ks[0][srow * 72 + scol]) = kr0;
    *(half8*)(&Ks[0][srow * 72 + scol + 32]) = kr1;
    *(half8*)(&VT[0][srow * 72 + scol]) = vr0;
    *(half8*)(&VT[0][srow * 72 + scol + 32]) = vr1;
  }
  float4 mk[4];
#pragma unroll
  for (int mt = 0; mt < 4; ++mt) mk[mt] = mkp[mt * 4 + quad];
  __syncthreads();  // tile0 + btab visible

  for (int kv0 = 0; kv0 < S; kv0 += 64) {
    const int buf = (kv0 >> 6) & 1;
    const bool more = (kv0 + 64) < S;
    // prefetch tile i+1 globals (consumed after compute)
    half8 kr0n, kr1n, vr0n, vr1n;
    float4 mkn[4];
    if (more) {
      kr0n = *(const half8*)(kg + (size_t)(kv0 + 64) * LD);
      kr1n = *(const half8*)(kg + (size_t)(kv0 + 64) * LD + 32);
      vr0n = *(const half8*)(vg + kv0 + 64);
      vr1n = *(const half8*)(vg + kv0 + 64 + 32);
#pragma unroll
      for (int mt = 0; mt < 4; ++mt) mkn[mt] = mkp[((kv0 + 64) >> 2) + mt * 4 + quad];
    }

    // ---- position-bias stream: odd 64-col chunks, 64 q-rows x 64 k per store-iter ----
    if (kv0 & 64) {
      const int diffw = kv0 - qrow0;
      float4* dst = bias_base + (kv0 >> 2);
      if (diffw >= 154) {  // min delta over tile = diffw - 63 >= 91 -> all future-clamp
        const float4 v = make_float4(c_fut, c_fut, c_fut, c_fut);
#pragma unroll
        for (int j = 0; j < 4; ++j) {
          int fi = j * 256 + tid;
          dst[(size_t)(fi >> 4) * 512 + (fi & 15)] = v;
        }
      } else if (diffw <= -154) {  // min (q-k) = -diffw - 63 >= 91 -> all past-clamp
        const float4 v = make_float4(c_past, c_past, c_past, c_past);
#pragma unroll
        for (int j = 0; j < 4; ++j) {
          int fi = j * 256 + tid;
          dst[(size_t)(fi >> 4) * 512 + (fi & 15)] = v;
        }
      } else {  // mixed tile: |delta| <= 216 -> btab[delta+256] in range
#pragma unroll
        for (int j = 0; j < 4; ++j) {
          int fi = j * 256 + tid;
          int row = fi >> 4, c4 = fi & 15;
          int q = qrow0 + row, k = kv0 + c4 * 4;
          float4 v;
          if (k - q >= 91) {
            v = make_float4(c_fut, c_fut, c_fut, c_fut);
          } else if (q - k - 3 >= 91) {
            v = make_float4(c_past, c_past, c_past, c_past);
          } else {
            int bi = k - q + 256;
            v.x = btab[bi + 0];
            v.y = btab[bi + 1];
            v.z = btab[bi + 2];
            v.w = btab[bi + 3];
          }
          dst[(size_t)row * 512 + c4] = v;
        }
      }
    }

    // S^T: sc[qt][mt][r] = score(kv = kv0+mt*16+quad*4+r, q = q0+wave*32+qt*16+l15)
    const _Float16* KsB = &Ks[buf][0];
    const _Float16* VTB = &VT[buf][0];
    v4f sc[2][4] = {};
#pragma unroll
    for (int kc = 0; kc < 2; ++kc)
#pragma unroll
      for (int mt = 0; mt < 4; ++mt) {
        half8 af = *(const half8*)(KsB + (mt * 16 + l15) * 72 + kc * 32 + quad * 8);
        sc[0][mt] = __builtin_amdgcn_mfma_f32_16x16x32_f16(af, bq[0][kc], sc[0][mt], 0, 0, 0);
        sc[1][mt] = __builtin_amdgcn_mfma_f32_16x16x32_f16(af, bq[1][kc], sc[1][mt], 0, 0, 0);
      }

    // bias + mask; block-uniform tile classification (mixed deltas fit btab[512])
    const int diff = kv0 - q0;
    const bool mixed = (diff >= -153) && (diff <= 217);
    const float cf = (diff >= 218) ? c_fut : c_past;
    v4f cm[4];
#pragma unroll
    for (int mt = 0; mt < 4; ++mt) {
      cm[mt][0] = mk[mt].x; cm[mt][1] = mk[mt].y; cm[mt][2] = mk[mt].z; cm[mt][3] = mk[mt].w;
      if (!mixed) {
        cm[mt][0] += cf; cm[mt][1] += cf; cm[mt][2] += cf; cm[mt][3] += cf;
      }
    }
    if (mixed) {
#pragma unroll
      for (int qt = 0; qt < 2; ++qt) {
        const int qq = q0 + wave * 32 + qt * 16 + l15;
#pragma unroll
        for (int mt = 0; mt < 4; ++mt) {
          int base = kv0 + mt * 16 + quad * 4 - qq + 256;
#pragma unroll
          for (int r = 0; r < 4; ++r) sc[qt][mt][r] += btab[base + r] + cm[mt][r];
        }
      }
    } else {
#pragma unroll
      for (int qt = 0; qt < 2; ++qt)
#pragma unroll
        for (int mt = 0; mt < 4; ++mt)
#pragma unroll
          for (int r = 0; r < 4; ++r) sc[qt][mt][r] += cm[mt][r];
    }

    // online softmax (one q per lane per qt; reduce across quads: xor 16, 32)
#pragma unroll
    for (int qt = 0; qt < 2; ++qt) {
      v4f m4 = sc[qt][0];
#pragma unroll
      for (int r = 0; r < 4; ++r) {
        m4[r] = fmaxf(m4[r], sc[qt][1][r]);
        m4[r] = fmaxf(m4[r], sc[qt][2][r]);
        m4[r] = fmaxf(m4[r], sc[qt][3][r]);
      }
      float mx = fmaxf(fmaxf(m4[0], m4[1]), fmaxf(m4[2], m4[3]));
      mx = fmaxf(mx, __shfl_xor(mx, 16, 64));
      mx = fmaxf(mx, __shfl_xor(mx, 32, 64));
      // exact defer-max: if no lane grew, alpha == 1 for every lane -> skip rescale
      if (!__all(mx <= mrun[qt])) {
        float mnew = fmaxf(mrun[qt], mx);
        float alpha = __expf(mrun[qt] - mnew);
        mrun[qt] = mnew;
        lrun[qt] *= alpha;
#pragma unroll
        for (int dt = 0; dt < 4; ++dt)
#pragma unroll
          for (int r = 0; r < 4; ++r) o[qt][dt][r] *= alpha;
      }
      const float mcur = mrun[qt];
      v4f s4 = {};
#pragma unroll
      for (int mt = 0; mt < 4; ++mt)
#pragma unroll
        for (int r = 0; r < 4; ++r) {
          float p = __expf(sc[qt][mt][r] - mcur);
          sc[qt][mt][r] = p;
          s4[r] += p;
        }
      float rs = (s4[0] + s4[1]) + (s4[2] + s4[3]);
      rs += __shfl_xor(rs, 16, 64);
      rs += __shfl_xor(rs, 32, 64);
      lrun[qt] += rs;
      // P write: 4 consecutive kv per lane -> packed b64 (own-wave rows only)
      const int prow = wave * 32 + qt * 16 + l15;
#pragma unroll
      for (int mt = 0; mt < 4; ++mt) {
        half4_t ph = {(_Float16)sc[qt][mt][0], (_Float16)sc[qt][mt][1],
                      (_Float16)sc[qt][mt][2], (_Float16)sc[qt][mt][3]};
        *(half4_t*)(Psh + prow * 72 + mt * 16 + quad * 4) = ph;
      }
    }
    // NO barrier: PV reads only this wave's own P rows (same-wave LDS RAW -> lgkmcnt)

    // O^T += V^T * P^T
#pragma unroll
    for (int kc = 0; kc < 2; ++kc) {
      half8 bp0 = *(const half8*)(Psh + (wave * 32 + l15) * 72 + kc * 32 + quad * 8);
      half8 bp1 = *(const half8*)(Psh + (wave * 32 + 16 + l15) * 72 + kc * 32 + quad * 8);
#pragma unroll
      for (int dt = 0; dt < 4; ++dt) {
        half8 av = *(const half8*)(VTB + (dt * 16 + l15) * 72 + kc * 32 + quad * 8);
        o[0][dt] = __builtin_amdgcn_mfma_f32_16x16x32_f16(av, bp0, o[0][dt], 0, 0, 0);
        o[1][dt] = __builtin_amdgcn_mfma_f32_16x16x32_f16(av, bp1, o[1][dt], 0, 0, 0);
      }
    }

    // stage tile i+1 into the other buffer; single lgkm-only barrier closes the
    // iteration (bias stores + prefetch loads need no vmcnt drain here)
    if (more) {
      _Float16* Kn = &Ks[buf ^ 1][0];
      _Float16* Vn = &VT[buf ^ 1][0];
      *(half8*)(Kn + srow * 72 + scol) = kr0n;
      *(half8*)(Kn + srow * 72 + scol + 32) = kr1n;
      *(half8*)(Vn + srow * 72 + scol) = vr0n;
      *(half8*)(Vn + srow * 72 + scol + 32) = vr1n;
      asm volatile("s_waitcnt lgkmcnt(0)\ns_barrier" ::: "memory");
#pragma unroll
      for (int mt = 0; mt < 4; ++mt) mk[mt] = mkn[mt];
    }
  }
  // epilogue: ctx[token][h*64+d], d = dt*16 + quad*4 + r
#pragma unroll
  for (int qt = 0; qt < 2; ++qt) {
    float inv = 1.0f / lrun[qt];
    const size_t token = (size_t)(b * S + q0 + wave * 32 + qt * 16 + l15);
#pragma unroll
    for (int dt = 0; dt < 4; ++dt) {
      half4_t hv = {(_Float16)(o[qt][dt][0] * inv), (_Float16)(o[qt][dt][1] * inv),
                    (_Float16)(o[qt][dt][2] * inv), (_Float16)(o[qt][dt][3] * inv)};
      *(half4_t*)(ctx + token * 1024 + h * 64 + dt * 16 + quad * 4) = hv;
    }
  }
}

extern "C" void kernel_launch(void* const* d_in, const int* in_sizes, int n_in,
                              void* d_out, int out_size, void* d_ws, size_t ws_size,
                              hipStream_t stream) {
  const float* hs = (const float*)d_in[0];
  const float* mask = (const float*)d_in[1];
  const float* Wq = (const float*)d_in[2];
  const float* Wk = (const float*)d_in[3];
  const float* Wv = (const float*)d_in[4];
  const float* Wo = (const float*)d_in[5];
  const float* rel = (const float*)d_in[6];
  float* out = (float*)d_out;

  // workspace layout (56 MB)
  char* ws = (char*)d_ws;
  _Float16* hsF = (_Float16*)(ws);                 // [4096,1024]   8 MB
  _Float16* wqkvT = (_Float16*)(ws + (8u << 20));  // [3072,1024]   6 MB
  _Float16* woT = (_Float16*)(ws + (14u << 20));   // [1024,1024]   2 MB
  _Float16* qkv = (_Float16*)(ws + (16u << 20));   // [4096,3072]  24 MB (V-part unused)
  _Float16* ctx = (_Float16*)(ws + (40u << 20));   // [4096,1024]   8 MB
  _Float16* vT = (_Float16*)(ws + (48u << 20));    // [2,16,64,2048] 8 MB

  // prep: hs convert + all 4 weight transposes in one dispatch
  k_prep<<<8192, 256, 0, stream>>>(hs, Wq, Wk, Wv, Wo, hsF, wqkvT, woT);

  // QKV projection fused with HALF the bias-output stream (even 64-col chunks);
  // V-range blocks write vT directly (transposed epilogue)
  k_gemm_qkv_bias<<<dim3(24, 32), 256, 0, stream>>>(hsF, wqkvT, qkv, vT, rel,
                                                    out + 4194304);
  // fused flash attention (double-buffered K/V, 1 barrier per kv tile) + the other
  // half of the bias stream (odd 64-col chunks)
  k_attn<<<dim3(16, 16, 2), 256, 0, stream>>>(qkv, vT, mask, rel, ctx, out + 4194304);
  // output projection
  k_gemm_n64<<<dim3(16, 32), 256, 0, stream>>>(ctx, woT, out, 1024, 1024);
}

// Round 4
// 421.093 us; speedup vs baseline: 1.0047x; 1.0047x over previous
//
#include <hip/hip_runtime.h>
#include <cstdint>

#define AS1 __attribute__((address_space(1)))
#define AS3 __attribute__((address_space(3)))

typedef _Float16 half8 __attribute__((ext_vector_type(8)));
typedef _Float16 half4_t __attribute__((ext_vector_type(4)));
typedef float v4f __attribute__((ext_vector_type(4)));

__device__ __forceinline__ void async_ld16(const void* g, void* l) {
  __builtin_amdgcn_global_load_lds((const AS1 uint32_t*)g, (AS3 uint32_t*)l, 16, 0, 0);
}

// T5 relative-position bucket for delta = k - q (bidirectional, 32 buckets, max_dist 128).
__device__ __forceinline__ int t5_bucket(int delta) {
  int n = -delta;  // n = q - k
  int ret = 0;
  if (n < 0) { ret = 16; n = -n; }
  if (n < 8) return n + ret;
  if (n >= 91) return 15 + ret;
  if ((n & (n - 1)) == 0) {
    int l = 31 - __clz(n);
    int v = 2 + 2 * l;
    return (v > 15 ? 15 : v) + ret;
  }
  int v = 8 + (int)(logf((float)n * 0.125f) * (8.0f / logf(16.0f)));
  return (v > 15 ? 15 : v) + ret;
}

// ---------------- prep: hs fp32->fp16 (x<4096) + 4 weight transposes (x>=4096) --------
__global__ void k_prep(const float* __restrict__ hs, const float* __restrict__ Wq,
                       const float* __restrict__ Wk, const float* __restrict__ Wv,
                       const float* __restrict__ Wo, _Float16* __restrict__ hsF,
                       _Float16* __restrict__ wqkvT, _Float16* __restrict__ woT) {
  const int tid = threadIdx.x;
  if (blockIdx.x < 4096) {
    int t = blockIdx.x * 256 + tid;
    float4 f = ((const float4*)hs)[t];
    half4_t h = {(_Float16)f.x, (_Float16)f.y, (_Float16)f.z, (_Float16)f.w};
    ((half4_t*)hsF)[t] = h;
    return;
  }
  __shared__ float tile[32][33];
  const int idx = blockIdx.x - 4096;
  const int z = idx >> 10, rem = idx & 1023;
  const float* src = (z == 0) ? Wq : (z == 1) ? Wk : (z == 2) ? Wv : Wo;
  _Float16* dst = (z < 3) ? (wqkvT + ((size_t)z << 20)) : woT;
  const int tx = tid & 31, ty = tid >> 5;
  const int bx = (rem & 31) * 32, by = (rem >> 5) * 32;
#pragma unroll
  for (int i = 0; i < 32; i += 8)
    tile[ty + i][tx] = src[(size_t)(by + ty + i) * 1024 + bx + tx];
  __syncthreads();
#pragma unroll
  for (int i = 0; i < 32; i += 8)
    dst[(size_t)(bx + ty + i) * 1024 + by + tx] = (_Float16)tile[tx][ty + i];
}

// ---------------- QKV GEMM fused with position-bias writer (EVEN 64-col chunks) -------
// 128x128 tile, BK=32, grid (24,32) = 768 blocks = 3/CU. Counted-vmcnt barrier (T4):
// staging loads are issued before the bias stores; barrier 2 waits vmcnt(2) so staging
// is complete while the 2 newest stores stay in flight across the barrier.
__global__ __launch_bounds__(256, 3) void k_gemm_qkv_bias(
    const _Float16* __restrict__ A, const _Float16* __restrict__ BT,
    _Float16* __restrict__ qkv, _Float16* __restrict__ vT,
    const float* __restrict__ rel, float* __restrict__ outb) {
  __shared__ __align__(16) _Float16 As[128 * 32];
  __shared__ __align__(16) _Float16 Bs[128 * 32];
  __shared__ float btab[256];  // bias vs delta in [-128,127] (mixed band only)
  const int tid = threadIdx.x;
  const int wave = tid >> 6, lane = tid & 63;
  const int l15 = lane & 15, quad = lane >> 4;
  const int m0 = blockIdx.y * 128, n0 = blockIdx.x * 128;
  const int wm = (wave >> 1) * 64, wn = (wave & 1) * 64;
  const int r0 = tid >> 2, c0 = (tid & 3) * 8;
  constexpr int K = 1024;

  const int bid = blockIdx.y * 24 + blockIdx.x;  // 0..767
  const bool do_bias = bid < 512;
  const int hB = bid >> 5;           // head for this block's bias slice
  const int qoff = (bid & 31) * 64;  // 64-q strip within the head
  float c_past = 0.f, c_fut = 0.f;
  if (do_bias) {
    btab[tid & 255] = rel[t5_bucket((tid & 255) - 128) * 16 + hB];
    c_past = rel[15 * 16 + hB];
    c_fut = rel[31 * 16 + hB];
  }

  v4f acc[4][4] = {};
  for (int k0 = 0; k0 < K; k0 += 32) {
    // barrier 1: all waves done READING As/Bs; no vmcnt wait -- older bias stores
    // keep draining in background.
    asm volatile("s_waitcnt lgkmcnt(0)\ns_barrier" ::: "memory");
    async_ld16(A + (size_t)(m0 + r0) * K + k0 + c0, (char*)As + (size_t)(wave * 64) * 16);
    async_ld16(A + (size_t)(m0 + 64 + r0) * K + k0 + c0,
               (char*)As + (size_t)(256 + wave * 64) * 16);
    async_ld16(BT + (size_t)(n0 + r0) * K + k0 + c0, (char*)Bs + (size_t)(wave * 64) * 16);
    async_ld16(BT + (size_t)(n0 + 64 + r0) * K + k0 + c0,
               (char*)Bs + (size_t)(256 + wave * 64) * 16);

    if (do_bias) {
      // keep the staging loads OLDER than the stores in the vmcnt queue
      __builtin_amdgcn_sched_barrier(0);
      const int iter = k0 >> 5;  // 0..31
#pragma unroll
      for (int j = 0; j < 2; ++j) {
        int fi = iter * 512 + j * 256 + tid;       // 0..16383 within this block's slice
        int qr = qoff + (fi >> 8);                 // q row (2 rows per iter)
        int c = fi & 255;                          // float4 col in even-chunk space
        int k4 = ((c >> 4) << 5) + (c & 15);       // float4 col in full 512-wide row
        int kb = k4 << 2;                          // k element
        float4 v;
        if (kb - qr >= 91) {
          v = make_float4(c_fut, c_fut, c_fut, c_fut);
        } else if (qr - kb - 3 >= 91) {
          v = make_float4(c_past, c_past, c_past, c_past);
        } else {
          v.x = btab[kb + 0 - qr + 128];
          v.y = btab[kb + 1 - qr + 128];
          v.z = btab[kb + 2 - qr + 128];
          v.w = btab[kb + 3 - qr + 128];
        }
        ((float4*)outb)[((size_t)hB * 2048 + qr) * 512 + k4] = v;
      }
      // barrier 2: queue = [ld x4 (oldest), st x2 (newest)]; in-order retirement:
      // vmcnt(2) => all 4 staging loads complete, 2 stores stay in flight.
      asm volatile("s_waitcnt vmcnt(2) lgkmcnt(0)\ns_barrier" ::: "memory");
    } else {
      asm volatile("s_waitcnt vmcnt(0) lgkmcnt(0)\ns_barrier" ::: "memory");
    }

    half8 af[4], bf[4];
#pragma unroll
    for (int mt = 0; mt < 4; ++mt)
      af[mt] = *(const half8*)(As + (wm + mt * 16 + l15) * 32 + quad * 8);
#pragma unroll
    for (int nt = 0; nt < 4; ++nt)
      bf[nt] = *(const half8*)(Bs + (wn + nt * 16 + l15) * 32 + quad * 8);
#pragma unroll
    for (int mt = 0; mt < 4; ++mt)
#pragma unroll
      for (int nt = 0; nt < 4; ++nt)
        acc[mt][nt] = __builtin_amdgcn_mfma_f32_16x16x32_f16(af[mt], bf[nt], acc[mt][nt], 0, 0, 0);
  }
  if (n0 >= 2048) {
    // V block: write vT[((b*16+h)*64+d)][s], 4 consecutive s per lane -> b64 stores
#pragma unroll
    for (int mt = 0; mt < 4; ++mt)
#pragma unroll
      for (int nt = 0; nt < 4; ++nt) {
        int col = n0 + wn + nt * 16 + l15 - 2048;  // h*64 + d
        int row0 = m0 + wm + mt * 16 + quad * 4;   // token
        int bb = row0 >> 11, s0 = row0 & 2047;
        half4_t hv = {(_Float16)acc[mt][nt][0], (_Float16)acc[mt][nt][1],
                      (_Float16)acc[mt][nt][2], (_Float16)acc[mt][nt][3]};
        *(half4_t*)(vT + ((size_t)bb * 1024 + col) * 2048 + s0) = hv;
      }
    return;
  }
#pragma unroll
  for (int mt = 0; mt < 4; ++mt)
#pragma unroll
    for (int nt = 0; nt < 4; ++nt)
#pragma unroll
      for (int r = 0; r < 4; ++r)
        qkv[(size_t)(m0 + wm + mt * 16 + quad * 4 + r) * 3072 + n0 + wn + nt * 16 + l15] =
            (_Float16)acc[mt][nt][r];
}

// ---------------- output projection GEMM: 128x64 tile ----------------
__global__ __launch_bounds__(256, 2) void k_gemm_n64(const _Float16* __restrict__ A,
                                                     const _Float16* __restrict__ BT,
                                                     float* __restrict__ C, int K, int ldc) {
  __shared__ __align__(16) _Float16 As[128 * 32];
  __shared__ __align__(16) _Float16 Bs[64 * 32];
  const int tid = threadIdx.x;
  const int wave = tid >> 6, lane = tid & 63;
  const int l15 = lane & 15, quad = lane >> 4;
  const int m0 = blockIdx.y * 128, n0 = blockIdx.x * 64;
  const int wm = (wave >> 1) * 64, wn = (wave & 1) * 32;
  const int r0 = tid >> 2, c0 = (tid & 3) * 8;
  v4f acc[4][2] = {};
  for (int k0 = 0; k0 < K; k0 += 32) {
    asm volatile("s_waitcnt lgkmcnt(0)\ns_barrier" ::: "memory");
    async_ld16(A + (size_t)(m0 + r0) * K + k0 + c0, (char*)As + (size_t)(wave * 64) * 16);
    async_ld16(A + (size_t)(m0 + 64 + r0) * K + k0 + c0,
               (char*)As + (size_t)(256 + wave * 64) * 16);
    async_ld16(BT + (size_t)(n0 + r0) * K + k0 + c0, (char*)Bs + (size_t)(wave * 64) * 16);
    asm volatile("s_waitcnt vmcnt(0) lgkmcnt(0)\ns_barrier" ::: "memory");
    half8 af[4], bf[2];
#pragma unroll
    for (int mt = 0; mt < 4; ++mt)
      af[mt] = *(const half8*)(As + (wm + mt * 16 + l15) * 32 + quad * 8);
#pragma unroll
    for (int nt = 0; nt < 2; ++nt)
      bf[nt] = *(const half8*)(Bs + (wn + nt * 16 + l15) * 32 + quad * 8);
#pragma unroll
    for (int mt = 0; mt < 4; ++mt)
#pragma unroll
      for (int nt = 0; nt < 2; ++nt)
        acc[mt][nt] = __builtin_amdgcn_mfma_f32_16x16x32_f16(af[mt], bf[nt], acc[mt][nt], 0, 0, 0);
  }
#pragma unroll
  for (int mt = 0; mt < 4; ++mt)
#pragma unroll
    for (int nt = 0; nt < 2; ++nt)
#pragma unroll
      for (int r = 0; r < 4; ++r)
        C[(size_t)(m0 + wm + mt * 16 + quad * 4 + r) * ldc + n0 + wn + nt * 16 + l15] =
            acc[mt][nt][r];
}

// ---------------- fused flash attention, double-buffered K/V, 1 barrier/iter ----------
// grid (16,16,2) = 512 blocks (2/CU), 4 waves, wave owns 32 q (qt=2).
// XCD-aware chunked swizzle (512%8==0 -> bijective): consecutive dispatch-order blocks
// round-robin the 8 XCDs, so the swizzle assigns each XCD 64 consecutive logical ids
// = 4 whole (h,b) pairs -> each XCD's L2 holds only 4 x 512 KB of K/V (L2-resident)
// instead of thrashing ~16 MB through 4 MB. s_setprio(1) wraps both MFMA clusters (T5:
// helps when independent blocks share a CU). P round-trip via LDS (known-good R1 path).
__global__ __launch_bounds__(256, 2) void k_attn(const _Float16* __restrict__ qkv,
                                                 const _Float16* __restrict__ vT,
                                                 const float* __restrict__ mask,
                                                 const float* __restrict__ rel,
                                                 _Float16* __restrict__ ctx,
                                                 float* __restrict__ outb) {
  constexpr int S = 2048, LD = 3072;
  __shared__ __align__(16) _Float16 Ks[2][64 * 72];  // [buf][kv][d] pad->LD 72
  __shared__ __align__(16) _Float16 VT[2][64 * 72];  // [buf][d][kv]
  __shared__ __align__(16) _Float16 Psh[128 * 72];   // [q][kv] per-wave-owned rows
  __shared__ float btab[512];                        // bias vs delta in [-256,255]
  const int tid = threadIdx.x, wave = tid >> 6, lane = tid & 63;
  const int l15 = lane & 15, quad = lane >> 4;
  // XCD-aware chunked remap of the 512-block grid (bijective since 512 % 8 == 0)
  const int flat = blockIdx.x + 16 * (blockIdx.y + 16 * blockIdx.z);
  const int swz = (flat & 7) * 64 + (flat >> 3);
  const int q0 = (swz & 15) * 128, h = (swz >> 4) & 15, b = swz >> 8;

  for (int j = tid; j < 512; j += 256) btab[j] = rel[t5_bucket(j - 256) * 16 + h];
  const float c_past = rel[15 * 16 + h];  // q - k >= 91
  const float c_fut = rel[31 * 16 + h];   // k - q >= 91

  half8 bq[2][2];
#pragma unroll
  for (int qt = 0; qt < 2; ++qt) {
    const _Float16* qp = qkv + (size_t)(b * S + q0 + wave * 32 + qt * 16 + l15) * LD + h * 64;
    bq[qt][0] = *(const half8*)(qp + quad * 8);
    bq[qt][1] = *(const half8*)(qp + 32 + quad * 8);
  }
  v4f o[2][4] = {};
  float mrun[2] = {-INFINITY, -INFINITY};
  float lrun[2] = {0.f, 0.f};

  const int srow = tid >> 2, scol = (tid & 3) * 8;
  const _Float16* kg = qkv + (size_t)(b * S + srow) * LD + 1024 + h * 64 + scol;
  const _Float16* vg = vT + ((size_t)((b * 16 + h) * 64 + srow)) * S + scol;
  const float4* mkp = (const float4*)(mask + (size_t)b * S);

  // bias-writer constants: this block owns q-rows [qrow0, qrow0+64) of head h
  const int qrow0 = q0 + b * 64;
  float4* const bias_base = (float4*)outb + ((size_t)h * 2048 + qrow0) * 512;

  // stage tile 0 into buf 0
  {
    half8 kr0 = *(const half8*)(kg);
    half8 kr1 = *(const half8*)(kg + 32);
    half8 vr0 = *(const half8*)(vg);
    half8 vr1 = *(const half8*)(vg + 32);
    *(half8*)(&Ks[0][srow * 72 + scol]) = kr0;
    *(half8*)(&Ks[0][srow * 72 + scol + 32]) = kr1;
    *(half8*)(&VT[0][srow * 72 + scol]) = vr0;
    *(half8*)(&VT[0][srow * 72 + scol + 32]) = vr1;
  }
  float4 mk[4];
#pragma unroll
  for (int mt = 0; mt < 4; ++mt) mk[mt] = mkp[mt * 4 + quad];
  __syncthreads();  // tile0 + btab visible

  for (int kv0 = 0; kv0 < S; kv0 += 64) {
    const int buf = (kv0 >> 6) & 1;
    const bool more = (kv0 + 64) < S;
    // prefetch tile i+1 globals (consumed after compute)
    half8 kr0n, kr1n, vr0n, vr1n;
    float4 mkn[4];
    if (more) {
      kr0n = *(const half8*)(kg + (size_t)(kv0 + 64) * LD);
      kr1n = *(const half8*)(kg + (size_t)(kv0 + 64) * LD + 32);
      vr0n = *(const half8*)(vg + kv0 + 64);
      vr1n = *(const half8*)(vg + kv0 + 64 + 32);
#pragma unroll
      for (int mt = 0; mt < 4; ++mt) mkn[mt] = mkp[((kv0 + 64) >> 2) + mt * 4 + quad];
    }

    // ---- position-bias stream: odd 64-col chunks, 64 q-rows x 64 k per store-iter ----
    if (kv0 & 64) {
      const int diffw = kv0 - qrow0;
      float4* dst = bias_base + (kv0 >> 2);
      if (diffw >= 154) {
        const float4 v = make_float4(c_fut, c_fut, c_fut, c_fut);
#pragma unroll
        for (int j = 0; j < 4; ++j) {
          int fi = j * 256 + tid;
          dst[(size_t)(fi >> 4) * 512 + (fi & 15)] = v;
        }
      } else if (diffw <= -154) {
        const float4 v = make_float4(c_past, c_past, c_past, c_past);
#pragma unroll
        for (int j = 0; j < 4; ++j) {
          int fi = j * 256 + tid;
          dst[(size_t)(fi >> 4) * 512 + (fi & 15)] = v;
        }
      } else {  // mixed tile: |delta| <= 216 -> btab[delta+256] in range
#pragma unroll
        for (int j = 0; j < 4; ++j) {
          int fi = j * 256 + tid;
          int row = fi >> 4, c4 = fi & 15;
          int q = qrow0 + row, k = kv0 + c4 * 4;
          float4 v;
          if (k - q >= 91) {
            v = make_float4(c_fut, c_fut, c_fut, c_fut);
          } else if (q - k - 3 >= 91) {
            v = make_float4(c_past, c_past, c_past, c_past);
          } else {
            int bi = k - q + 256;
            v.x = btab[bi + 0];
            v.y = btab[bi + 1];
            v.z = btab[bi + 2];
            v.w = btab[bi + 3];
          }
          dst[(size_t)row * 512 + c4] = v;
        }
      }
    }

    // S^T: sc[qt][mt][r] = score(kv = kv0+mt*16+quad*4+r, q = q0+wave*32+qt*16+l15)
    const _Float16* KsB = &Ks[buf][0];
    const _Float16* VTB = &VT[buf][0];
    v4f sc[2][4] = {};
    __builtin_amdgcn_s_setprio(1);
#pragma unroll
    for (int kc = 0; kc < 2; ++kc)
#pragma unroll
      for (int mt = 0; mt < 4; ++mt) {
        half8 af = *(const half8*)(KsB + (mt * 16 + l15) * 72 + kc * 32 + quad * 8);
        sc[0][mt] = __builtin_amdgcn_mfma_f32_16x16x32_f16(af, bq[0][kc], sc[0][mt], 0, 0, 0);
        sc[1][mt] = __builtin_amdgcn_mfma_f32_16x16x32_f16(af, bq[1][kc], sc[1][mt], 0, 0, 0);
      }
    __builtin_amdgcn_s_setprio(0);

    // bias + mask; block-uniform tile classification (mixed deltas fit btab[512])
    const int diff = kv0 - q0;
    const bool mixed = (diff >= -153) && (diff <= 217);
    const float cf = (diff >= 218) ? c_fut : c_past;
    v4f cm[4];
#pragma unroll
    for (int mt = 0; mt < 4; ++mt) {
      cm[mt][0] = mk[mt].x; cm[mt][1] = mk[mt].y; cm[mt][2] = mk[mt].z; cm[mt][3] = mk[mt].w;
      if (!mixed) {
        cm[mt][0] += cf; cm[mt][1] += cf; cm[mt][2] += cf; cm[mt][3] += cf;
      }
    }
    if (mixed) {
#pragma unroll
      for (int qt = 0; qt < 2; ++qt) {
        const int qq = q0 + wave * 32 + qt * 16 + l15;
#pragma unroll
        for (int mt = 0; mt < 4; ++mt) {
          int base = kv0 + mt * 16 + quad * 4 - qq + 256;
#pragma unroll
          for (int r = 0; r < 4; ++r) sc[qt][mt][r] += btab[base + r] + cm[mt][r];
        }
      }
    } else {
#pragma unroll
      for (int qt = 0; qt < 2; ++qt)
#pragma unroll
        for (int mt = 0; mt < 4; ++mt)
#pragma unroll
          for (int r = 0; r < 4; ++r) sc[qt][mt][r] += cm[mt][r];
    }

    // online softmax (one q per lane per qt; reduce across quads: xor 16, 32)
#pragma unroll
    for (int qt = 0; qt < 2; ++qt) {
      v4f m4 = sc[qt][0];
#pragma unroll
      for (int r = 0; r < 4; ++r) {
        m4[r] = fmaxf(m4[r], sc[qt][1][r]);
        m4[r] = fmaxf(m4[r], sc[qt][2][r]);
        m4[r] = fmaxf(m4[r], sc[qt][3][r]);
      }
      float mx = fmaxf(fmaxf(m4[0], m4[1]), fmaxf(m4[2], m4[3]));
      mx = fmaxf(mx, __shfl_xor(mx, 16, 64));
      mx = fmaxf(mx, __shfl_xor(mx, 32, 64));
      // exact defer-max: if no lane grew, alpha == 1 for every lane -> skip rescale
      if (!__all(mx <= mrun[qt])) {
        float mnew = fmaxf(mrun[qt], mx);
        float alpha = __expf(mrun[qt] - mnew);
        mrun[qt] = mnew;
        lrun[qt] *= alpha;
#pragma unroll
        for (int dt = 0; dt < 4; ++dt)
#pragma unroll
          for (int r = 0; r < 4; ++r) o[qt][dt][r] *= alpha;
      }
      const float mcur = mrun[qt];
      v4f s4 = {};
#pragma unroll
      for (int mt = 0; mt < 4; ++mt)
#pragma unroll
        for (int r = 0; r < 4; ++r) {
          float p = __expf(sc[qt][mt][r] - mcur);
          sc[qt][mt][r] = p;
          s4[r] += p;
        }
      float rs = (s4[0] + s4[1]) + (s4[2] + s4[3]);
      rs += __shfl_xor(rs, 16, 64);
      rs += __shfl_xor(rs, 32, 64);
      lrun[qt] += rs;
      // P write: 4 consecutive kv per lane -> packed b64 (own-wave rows only)
      const int prow = wave * 32 + qt * 16 + l15;
#pragma unroll
      for (int mt = 0; mt < 4; ++mt) {
        half4_t ph = {(_Float16)sc[qt][mt][0], (_Float16)sc[qt][mt][1],
                      (_Float16)sc[qt][mt][2], (_Float16)sc[qt][mt][3]};
        *(half4_t*)(Psh + prow * 72 + mt * 16 + quad * 4) = ph;
      }
    }
    // NO barrier: PV reads only this wave's own P rows (same-wave LDS RAW -> lgkmcnt)

    // O^T += V^T * P^T
    __builtin_amdgcn_s_setprio(1);
#pragma unroll
    for (int kc = 0; kc < 2; ++kc) {
      half8 bp0 = *(const half8*)(Psh + (wave * 32 + l15) * 72 + kc * 32 + quad * 8);
      half8 bp1 = *(const half8*)(Psh + (wave * 32 + 16 + l15) * 72 + kc * 32 + quad * 8);
#pragma unroll
      for (int dt = 0; dt < 4; ++dt) {
        half8 av = *(const half8*)(VTB + (dt * 16 + l15) * 72 + kc * 32 + quad * 8);
        o[0][dt] = __builtin_amdgcn_mfma_f32_16x16x32_f16(av, bp0, o[0][dt], 0, 0, 0);
        o[1][dt] = __builtin_amdgcn_mfma_f32_16x16x32_f16(av, bp1, o[1][dt], 0, 0, 0);
      }
    }
    __builtin_amdgcn_s_setprio(0);

    // stage tile i+1 into the other buffer; single lgkm-only barrier closes the iter
    if (more) {
      _Float16* Kn = &Ks[buf ^ 1][0];
      _Float16* Vn = &VT[buf ^ 1][0];
      *(half8*)(Kn + srow * 72 + scol) = kr0n;
      *(half8*)(Kn + srow * 72 + scol + 32) = kr1n;
      *(half8*)(Vn + srow * 72 + scol) = vr0n;
      *(half8*)(Vn + srow * 72 + scol + 32) = vr1n;
      asm volatile("s_waitcnt lgkmcnt(0)\ns_barrier" ::: "memory");
#pragma unroll
      for (int mt = 0; mt < 4; ++mt) mk[mt] = mkn[mt];
    }
  }
  // epilogue: ctx[token][h*64+d], d = dt*16 + quad*4 + r
#pragma unroll
  for (int qt = 0; qt < 2; ++qt) {
    float inv = 1.0f / lrun[qt];
    const size_t token = (size_t)(b * S + q0 + wave * 32 + qt * 16 + l15);
#pragma unroll
    for (int dt = 0; dt < 4; ++dt) {
      half4_t hv = {(_Float16)(o[qt][dt][0] * inv), (_Float16)(o[qt][dt][1] * inv),
                    (_Float16)(o[qt][dt][2] * inv), (_Float16)(o[qt][dt][3] * inv)};
      *(half4_t*)(ctx + token * 1024 + h * 64 + dt * 16 + quad * 4) = hv;
    }
  }
}

extern "C" void kernel_launch(void* const* d_in, const int* in_sizes, int n_in,
                              void* d_out, int out_size, void* d_ws, size_t ws_size,
                              hipStream_t stream) {
  const float* hs = (const float*)d_in[0];
  const float* mask = (const float*)d_in[1];
  const float* Wq = (const float*)d_in[2];
  const float* Wk = (const float*)d_in[3];
  const float* Wv = (const float*)d_in[4];
  const float* Wo = (const float*)d_in[5];
  const float* rel = (const float*)d_in[6];
  float* out = (float*)d_out;

  // workspace layout (56 MB)
  char* ws = (char*)d_ws;
  _Float16* hsF = (_Float16*)(ws);                 // [4096,1024]   8 MB
  _Float16* wqkvT = (_Float16*)(ws + (8u << 20));  // [3072,1024]   6 MB
  _Float16* woT = (_Float16*)(ws + (14u << 20));   // [1024,1024]   2 MB
  _Float16* qkv = (_Float16*)(ws + (16u << 20));   // [4096,3072]  24 MB (V-part unused)
  _Float16* ctx = (_Float16*)(ws + (40u << 20));   // [4096,1024]   8 MB
  _Float16* vT = (_Float16*)(ws + (48u << 20));    // [2,16,64,2048] 8 MB

  // prep: hs convert + all 4 weight transposes in one dispatch
  k_prep<<<8192, 256, 0, stream>>>(hs, Wq, Wk, Wv, Wo, hsF, wqkvT, woT);

  // QKV projection fused with HALF the bias-output stream (even 64-col chunks);
  // V-range blocks write vT directly (transposed epilogue)
  k_gemm_qkv_bias<<<dim3(24, 32), 256, 0, stream>>>(hsF, wqkvT, qkv, vT, rel,
                                                    out + 4194304);
  // fused flash attention (XCD-swizzled, setprio'd MFMA clusters) + the other
  // half of the bias stream (odd 64-col chunks)
  k_attn<<<dim3(16, 16, 2), 256, 0, stream>>>(qkv, vT, mask, rel, ctx, out + 4194304);
  // output projection
  k_gemm_n64<<<dim3(16, 32), 256, 0, stream>>>(ctx, woT, out, 1024, 1024);
}

// Round 5
// 420.712 us; speedup vs baseline: 1.0056x; 1.0009x over previous
//
#include <hip/hip_runtime.h>
#include <cstdint>

#define AS1 __attribute__((address_space(1)))
#define AS3 __attribute__((address_space(3)))

typedef _Float16 half8 __attribute__((ext_vector_type(8)));
typedef _Float16 half4_t __attribute__((ext_vector_type(4)));
typedef float v4f __attribute__((ext_vector_type(4)));

__device__ __forceinline__ void async_ld16(const void* g, void* l) {
  __builtin_amdgcn_global_load_lds((const AS1 uint32_t*)g, (AS3 uint32_t*)l, 16, 0, 0);
}

// T5 relative-position bucket for delta = k - q (bidirectional, 32 buckets, max_dist 128).
__device__ __forceinline__ int t5_bucket(int delta) {
  int n = -delta;  // n = q - k
  int ret = 0;
  if (n < 0) { ret = 16; n = -n; }
  if (n < 8) return n + ret;
  if (n >= 91) return 15 + ret;
  if ((n & (n - 1)) == 0) {
    int l = 31 - __clz(n);
    int v = 2 + 2 * l;
    return (v > 15 ? 15 : v) + ret;
  }
  int v = 8 + (int)(logf((float)n * 0.125f) * (8.0f / logf(16.0f)));
  return (v > 15 ? 15 : v) + ret;
}

// ---------------- prep: hs fp32->fp16 (x<4096) + 4 weight transposes (x>=4096) --------
__global__ void k_prep(const float* __restrict__ hs, const float* __restrict__ Wq,
                       const float* __restrict__ Wk, const float* __restrict__ Wv,
                       const float* __restrict__ Wo, _Float16* __restrict__ hsF,
                       _Float16* __restrict__ wqkvT, _Float16* __restrict__ woT) {
  const int tid = threadIdx.x;
  if (blockIdx.x < 4096) {
    int t = blockIdx.x * 256 + tid;
    float4 f = ((const float4*)hs)[t];
    half4_t h = {(_Float16)f.x, (_Float16)f.y, (_Float16)f.z, (_Float16)f.w};
    ((half4_t*)hsF)[t] = h;
    return;
  }
  __shared__ float tile[32][33];
  const int idx = blockIdx.x - 4096;
  const int z = idx >> 10, rem = idx & 1023;
  const float* src = (z == 0) ? Wq : (z == 1) ? Wk : (z == 2) ? Wv : Wo;
  _Float16* dst = (z < 3) ? (wqkvT + ((size_t)z << 20)) : woT;
  const int tx = tid & 31, ty = tid >> 5;
  const int bx = (rem & 31) * 32, by = (rem >> 5) * 32;
#pragma unroll
  for (int i = 0; i < 32; i += 8)
    tile[ty + i][tx] = src[(size_t)(by + ty + i) * 1024 + bx + tx];
  __syncthreads();
#pragma unroll
  for (int i = 0; i < 32; i += 8)
    dst[(size_t)(bx + ty + i) * 1024 + by + tx] = (_Float16)tile[tx][ty + i];
}

// ---------------- QKV GEMM fused with position-bias writer (EVEN 64-col chunks) -------
// 128x128 tile, BK=32, grid (24,32) = 768 blocks = 3/CU. Counted-vmcnt barrier (T4):
// staging loads are issued before the bias stores; barrier 2 waits vmcnt(2) so staging
// is complete while the 2 newest stores stay in flight across the barrier.
__global__ __launch_bounds__(256, 3) void k_gemm_qkv_bias(
    const _Float16* __restrict__ A, const _Float16* __restrict__ BT,
    _Float16* __restrict__ qkv, _Float16* __restrict__ vT,
    const float* __restrict__ rel, float* __restrict__ outb) {
  __shared__ __align__(16) _Float16 As[128 * 32];
  __shared__ __align__(16) _Float16 Bs[128 * 32];
  __shared__ float btab[256];  // bias vs delta in [-128,127] (mixed band only)
  const int tid = threadIdx.x;
  const int wave = tid >> 6, lane = tid & 63;
  const int l15 = lane & 15, quad = lane >> 4;
  const int m0 = blockIdx.y * 128, n0 = blockIdx.x * 128;
  const int wm = (wave >> 1) * 64, wn = (wave & 1) * 64;
  const int r0 = tid >> 2, c0 = (tid & 3) * 8;
  constexpr int K = 1024;

  const int bid = blockIdx.y * 24 + blockIdx.x;  // 0..767
  const bool do_bias = bid < 512;
  const int hB = bid >> 5;           // head for this block's bias slice
  const int qoff = (bid & 31) * 64;  // 64-q strip within the head
  float c_past = 0.f, c_fut = 0.f;
  if (do_bias) {
    btab[tid & 255] = rel[t5_bucket((tid & 255) - 128) * 16 + hB];
    c_past = rel[15 * 16 + hB];
    c_fut = rel[31 * 16 + hB];
  }

  v4f acc[4][4] = {};
  for (int k0 = 0; k0 < K; k0 += 32) {
    // barrier 1: all waves done READING As/Bs; no vmcnt wait -- older bias stores
    // keep draining in background.
    asm volatile("s_waitcnt lgkmcnt(0)\ns_barrier" ::: "memory");
    async_ld16(A + (size_t)(m0 + r0) * K + k0 + c0, (char*)As + (size_t)(wave * 64) * 16);
    async_ld16(A + (size_t)(m0 + 64 + r0) * K + k0 + c0,
               (char*)As + (size_t)(256 + wave * 64) * 16);
    async_ld16(BT + (size_t)(n0 + r0) * K + k0 + c0, (char*)Bs + (size_t)(wave * 64) * 16);
    async_ld16(BT + (size_t)(n0 + 64 + r0) * K + k0 + c0,
               (char*)Bs + (size_t)(256 + wave * 64) * 16);

    if (do_bias) {
      // keep the staging loads OLDER than the stores in the vmcnt queue
      __builtin_amdgcn_sched_barrier(0);
      const int iter = k0 >> 5;  // 0..31
#pragma unroll
      for (int j = 0; j < 2; ++j) {
        int fi = iter * 512 + j * 256 + tid;       // 0..16383 within this block's slice
        int qr = qoff + (fi >> 8);                 // q row (2 rows per iter)
        int c = fi & 255;                          // float4 col in even-chunk space
        int k4 = ((c >> 4) << 5) + (c & 15);       // float4 col in full 512-wide row
        int kb = k4 << 2;                          // k element
        float4 v;
        if (kb - qr >= 91) {
          v = make_float4(c_fut, c_fut, c_fut, c_fut);
        } else if (qr - kb - 3 >= 91) {
          v = make_float4(c_past, c_past, c_past, c_past);
        } else {
          v.x = btab[kb + 0 - qr + 128];
          v.y = btab[kb + 1 - qr + 128];
          v.z = btab[kb + 2 - qr + 128];
          v.w = btab[kb + 3 - qr + 128];
        }
        ((float4*)outb)[((size_t)hB * 2048 + qr) * 512 + k4] = v;
      }
      // barrier 2: queue = [ld x4 (oldest), st x2 (newest)]; in-order retirement:
      // vmcnt(2) => all 4 staging loads complete, 2 stores stay in flight.
      asm volatile("s_waitcnt vmcnt(2) lgkmcnt(0)\ns_barrier" ::: "memory");
    } else {
      asm volatile("s_waitcnt vmcnt(0) lgkmcnt(0)\ns_barrier" ::: "memory");
    }

    half8 af[4], bf[4];
#pragma unroll
    for (int mt = 0; mt < 4; ++mt)
      af[mt] = *(const half8*)(As + (wm + mt * 16 + l15) * 32 + quad * 8);
#pragma unroll
    for (int nt = 0; nt < 4; ++nt)
      bf[nt] = *(const half8*)(Bs + (wn + nt * 16 + l15) * 32 + quad * 8);
#pragma unroll
    for (int mt = 0; mt < 4; ++mt)
#pragma unroll
      for (int nt = 0; nt < 4; ++nt)
        acc[mt][nt] = __builtin_amdgcn_mfma_f32_16x16x32_f16(af[mt], bf[nt], acc[mt][nt], 0, 0, 0);
  }
  if (n0 >= 2048) {
    // V block: write vT[((b*16+h)*64+d)][s], 4 consecutive s per lane -> b64 stores
#pragma unroll
    for (int mt = 0; mt < 4; ++mt)
#pragma unroll
      for (int nt = 0; nt < 4; ++nt) {
        int col = n0 + wn + nt * 16 + l15 - 2048;  // h*64 + d
        int row0 = m0 + wm + mt * 16 + quad * 4;   // token
        int bb = row0 >> 11, s0 = row0 & 2047;
        half4_t hv = {(_Float16)acc[mt][nt][0], (_Float16)acc[mt][nt][1],
                      (_Float16)acc[mt][nt][2], (_Float16)acc[mt][nt][3]};
        *(half4_t*)(vT + ((size_t)bb * 1024 + col) * 2048 + s0) = hv;
      }
    return;
  }
#pragma unroll
  for (int mt = 0; mt < 4; ++mt)
#pragma unroll
    for (int nt = 0; nt < 4; ++nt)
#pragma unroll
      for (int r = 0; r < 4; ++r)
        qkv[(size_t)(m0 + wm + mt * 16 + quad * 4 + r) * 3072 + n0 + wn + nt * 16 + l15] =
            (_Float16)acc[mt][nt][r];
}

// ---------------- output projection GEMM: 128x64 tile ----------------
__global__ __launch_bounds__(256, 2) void k_gemm_n64(const _Float16* __restrict__ A,
                                                     const _Float16* __restrict__ BT,
                                                     float* __restrict__ C, int K, int ldc) {
  __shared__ __align__(16) _Float16 As[128 * 32];
  __shared__ __align__(16) _Float16 Bs[64 * 32];
  const int tid = threadIdx.x;
  const int wave = tid >> 6, lane = tid & 63;
  const int l15 = lane & 15, quad = lane >> 4;
  const int m0 = blockIdx.y * 128, n0 = blockIdx.x * 64;
  const int wm = (wave >> 1) * 64, wn = (wave & 1) * 32;
  const int r0 = tid >> 2, c0 = (tid & 3) * 8;
  v4f acc[4][2] = {};
  for (int k0 = 0; k0 < K; k0 += 32) {
    asm volatile("s_waitcnt lgkmcnt(0)\ns_barrier" ::: "memory");
    async_ld16(A + (size_t)(m0 + r0) * K + k0 + c0, (char*)As + (size_t)(wave * 64) * 16);
    async_ld16(A + (size_t)(m0 + 64 + r0) * K + k0 + c0,
               (char*)As + (size_t)(256 + wave * 64) * 16);
    async_ld16(BT + (size_t)(n0 + r0) * K + k0 + c0, (char*)Bs + (size_t)(wave * 64) * 16);
    asm volatile("s_waitcnt vmcnt(0) lgkmcnt(0)\ns_barrier" ::: "memory");
    half8 af[4], bf[2];
#pragma unroll
    for (int mt = 0; mt < 4; ++mt)
      af[mt] = *(const half8*)(As + (wm + mt * 16 + l15) * 32 + quad * 8);
#pragma unroll
    for (int nt = 0; nt < 2; ++nt)
      bf[nt] = *(const half8*)(Bs + (wn + nt * 16 + l15) * 32 + quad * 8);
#pragma unroll
    for (int mt = 0; mt < 4; ++mt)
#pragma unroll
      for (int nt = 0; nt < 2; ++nt)
        acc[mt][nt] = __builtin_amdgcn_mfma_f32_16x16x32_f16(af[mt], bf[nt], acc[mt][nt], 0, 0, 0);
  }
#pragma unroll
  for (int mt = 0; mt < 4; ++mt)
#pragma unroll
    for (int nt = 0; nt < 2; ++nt)
#pragma unroll
      for (int r = 0; r < 4; ++r)
        C[(size_t)(m0 + wm + mt * 16 + quad * 4 + r) * ldc + n0 + wn + nt * 16 + l15] =
            acc[mt][nt][r];
}

// ---------------- fused flash attention: 8 waves x 16 q-rows, 4 waves/SIMD -----------
// grid (16,16,2) = 512 blocks (2/CU by LDS), 512 threads. Same 128-q tile, same kv loop,
// same arithmetic per q (old (wave,qt) group == new wave 2w+qt -> bit-identical output),
// but sharded over 8 waves of 16 q-rows: per-thread state halves, and occupancy doubles
// to 4 waves/SIMD -- twice the independent streams to hide the per-iteration
// MFMA->softmax->LDS-RAW->MFMA latency chain that made 2 waves/SIMD latency-bound.
// XCD-aware chunked swizzle kept; setprio kept; P round-trip via LDS (known-good).
__global__ __launch_bounds__(512, 4) void k_attn(const _Float16* __restrict__ qkv,
                                                 const _Float16* __restrict__ vT,
                                                 const float* __restrict__ mask,
                                                 const float* __restrict__ rel,
                                                 _Float16* __restrict__ ctx,
                                                 float* __restrict__ outb) {
  constexpr int S = 2048, LD = 3072;
  __shared__ __align__(16) _Float16 Ks[2][64 * 72];  // [buf][kv][d] pad->LD 72
  __shared__ __align__(16) _Float16 VT[2][64 * 72];  // [buf][d][kv]
  __shared__ __align__(16) _Float16 Psh[128 * 72];   // [q][kv] per-wave-owned rows
  __shared__ float btab[512];                        // bias vs delta in [-256,255]
  const int tid = threadIdx.x, wave = tid >> 6, lane = tid & 63;
  const int l15 = lane & 15, quad = lane >> 4;
  // XCD-aware chunked remap of the 512-block grid (bijective since 512 % 8 == 0)
  const int flat = blockIdx.x + 16 * (blockIdx.y + 16 * blockIdx.z);
  const int swz = (flat & 7) * 64 + (flat >> 3);
  const int q0 = (swz & 15) * 128, h = (swz >> 4) & 15, b = swz >> 8;

  btab[tid] = rel[t5_bucket((int)tid - 256) * 16 + h];
  const float c_past = rel[15 * 16 + h];  // q - k >= 91
  const float c_fut = rel[31 * 16 + h];   // k - q >= 91

  // wave owns q rows [q0 + wave*16, q0 + wave*16 + 16)
  half8 bq[2];
  {
    const _Float16* qp = qkv + (size_t)(b * S + q0 + wave * 16 + l15) * LD + h * 64;
    bq[0] = *(const half8*)(qp + quad * 8);
    bq[1] = *(const half8*)(qp + 32 + quad * 8);
  }
  v4f o[4] = {};
  float mrun = -INFINITY;
  float lrun = 0.f;

  // staging shard: 512 threads cover the 64x64 tile with one half8 each
  const int srow = tid >> 3, scol = (tid & 7) * 8;
  const _Float16* kg = qkv + (size_t)(b * S + srow) * LD + 1024 + h * 64 + scol;
  const _Float16* vg = vT + ((size_t)((b * 16 + h) * 64 + srow)) * S + scol;
  const float4* mkp = (const float4*)(mask + (size_t)b * S);

  // bias-writer constants: this block owns q-rows [qrow0, qrow0+64) of head h
  const int qrow0 = q0 + b * 64;
  float4* const bias_base = (float4*)outb + ((size_t)h * 2048 + qrow0) * 512;

  // stage tile 0 into buf 0
  {
    half8 kr = *(const half8*)(kg);
    half8 vr = *(const half8*)(vg);
    *(half8*)(&Ks[0][srow * 72 + scol]) = kr;
    *(half8*)(&VT[0][srow * 72 + scol]) = vr;
  }
  float4 mk[4];
#pragma unroll
  for (int mt = 0; mt < 4; ++mt) mk[mt] = mkp[mt * 4 + quad];
  __syncthreads();  // tile0 + btab visible

  for (int kv0 = 0; kv0 < S; kv0 += 64) {
    const int buf = (kv0 >> 6) & 1;
    const bool more = (kv0 + 64) < S;
    // prefetch tile i+1 globals (consumed after compute)
    half8 krn, vrn;
    float4 mkn[4];
    if (more) {
      krn = *(const half8*)(kg + (size_t)(kv0 + 64) * LD);
      vrn = *(const half8*)(vg + kv0 + 64);
#pragma unroll
      for (int mt = 0; mt < 4; ++mt) mkn[mt] = mkp[((kv0 + 64) >> 2) + mt * 4 + quad];
    }

    // ---- position-bias stream: odd 64-col chunks, 64 q-rows x 64 k per store-iter ----
    if (kv0 & 64) {
      const int diffw = kv0 - qrow0;
      float4* dst = bias_base + (kv0 >> 2);
      if (diffw >= 154) {
        const float4 v = make_float4(c_fut, c_fut, c_fut, c_fut);
#pragma unroll
        for (int j = 0; j < 2; ++j) {
          int fi = j * 512 + tid;
          dst[(size_t)(fi >> 4) * 512 + (fi & 15)] = v;
        }
      } else if (diffw <= -154) {
        const float4 v = make_float4(c_past, c_past, c_past, c_past);
#pragma unroll
        for (int j = 0; j < 2; ++j) {
          int fi = j * 512 + tid;
          dst[(size_t)(fi >> 4) * 512 + (fi & 15)] = v;
        }
      } else {  // mixed tile: |delta| <= 216 -> btab[delta+256] in range
#pragma unroll
        for (int j = 0; j < 2; ++j) {
          int fi = j * 512 + tid;
          int row = fi >> 4, c4 = fi & 15;
          int q = qrow0 + row, k = kv0 + c4 * 4;
          float4 v;
          if (k - q >= 91) {
            v = make_float4(c_fut, c_fut, c_fut, c_fut);
          } else if (q - k - 3 >= 91) {
            v = make_float4(c_past, c_past, c_past, c_past);
          } else {
            int bi = k - q + 256;
            v.x = btab[bi + 0];
            v.y = btab[bi + 1];
            v.z = btab[bi + 2];
            v.w = btab[bi + 3];
          }
          dst[(size_t)row * 512 + c4] = v;
        }
      }
    }

    // S^T: sc[mt][r] = score(kv = kv0+mt*16+quad*4+r, q = q0+wave*16+l15)
    const _Float16* KsB = &Ks[buf][0];
    const _Float16* VTB = &VT[buf][0];
    v4f sc[4] = {};
    __builtin_amdgcn_s_setprio(1);
#pragma unroll
    for (int kc = 0; kc < 2; ++kc)
#pragma unroll
      for (int mt = 0; mt < 4; ++mt) {
        half8 af = *(const half8*)(KsB + (mt * 16 + l15) * 72 + kc * 32 + quad * 8);
        sc[mt] = __builtin_amdgcn_mfma_f32_16x16x32_f16(af, bq[kc], sc[mt], 0, 0, 0);
      }
    __builtin_amdgcn_s_setprio(0);

    // bias + mask; block-uniform tile classification (mixed deltas fit btab[512])
    const int diff = kv0 - q0;
    const bool mixed = (diff >= -153) && (diff <= 217);
    const float cf = (diff >= 218) ? c_fut : c_past;
    v4f cm[4];
#pragma unroll
    for (int mt = 0; mt < 4; ++mt) {
      cm[mt][0] = mk[mt].x; cm[mt][1] = mk[mt].y; cm[mt][2] = mk[mt].z; cm[mt][3] = mk[mt].w;
      if (!mixed) {
        cm[mt][0] += cf; cm[mt][1] += cf; cm[mt][2] += cf; cm[mt][3] += cf;
      }
    }
    if (mixed) {
      const int qq = q0 + wave * 16 + l15;
#pragma unroll
      for (int mt = 0; mt < 4; ++mt) {
        int base = kv0 + mt * 16 + quad * 4 - qq + 256;
#pragma unroll
        for (int r = 0; r < 4; ++r) sc[mt][r] += btab[base + r] + cm[mt][r];
      }
    } else {
#pragma unroll
      for (int mt = 0; mt < 4; ++mt)
#pragma unroll
        for (int r = 0; r < 4; ++r) sc[mt][r] += cm[mt][r];
    }

    // online softmax (one q per lane; reduce across quads: xor 16, 32)
    {
      v4f m4 = sc[0];
#pragma unroll
      for (int r = 0; r < 4; ++r) {
        m4[r] = fmaxf(m4[r], sc[1][r]);
        m4[r] = fmaxf(m4[r], sc[2][r]);
        m4[r] = fmaxf(m4[r], sc[3][r]);
      }
      float mx = fmaxf(fmaxf(m4[0], m4[1]), fmaxf(m4[2], m4[3]));
      mx = fmaxf(mx, __shfl_xor(mx, 16, 64));
      mx = fmaxf(mx, __shfl_xor(mx, 32, 64));
      // exact defer-max: if no lane grew, alpha == 1 for every lane -> skip rescale
      if (!__all(mx <= mrun)) {
        float mnew = fmaxf(mrun, mx);
        float alpha = __expf(mrun - mnew);
        mrun = mnew;
        lrun *= alpha;
#pragma unroll
        for (int dt = 0; dt < 4; ++dt)
#pragma unroll
          for (int r = 0; r < 4; ++r) o[dt][r] *= alpha;
      }
      const float mcur = mrun;
      v4f s4 = {};
#pragma unroll
      for (int mt = 0; mt < 4; ++mt)
#pragma unroll
        for (int r = 0; r < 4; ++r) {
          float p = __expf(sc[mt][r] - mcur);
          sc[mt][r] = p;
          s4[r] += p;
        }
      float rs = (s4[0] + s4[1]) + (s4[2] + s4[3]);
      rs += __shfl_xor(rs, 16, 64);
      rs += __shfl_xor(rs, 32, 64);
      lrun += rs;
      // P write: 4 consecutive kv per lane -> packed b64 (own-wave rows only)
      const int prow = wave * 16 + l15;
#pragma unroll
      for (int mt = 0; mt < 4; ++mt) {
        half4_t ph = {(_Float16)sc[mt][0], (_Float16)sc[mt][1],
                      (_Float16)sc[mt][2], (_Float16)sc[mt][3]};
        *(half4_t*)(Psh + prow * 72 + mt * 16 + quad * 4) = ph;
      }
    }
    // NO barrier: PV reads only this wave's own P rows (same-wave LDS RAW -> lgkmcnt)

    // O^T += V^T * P^T
    __builtin_amdgcn_s_setprio(1);
#pragma unroll
    for (int kc = 0; kc < 2; ++kc) {
      half8 bp = *(const half8*)(Psh + (wave * 16 + l15) * 72 + kc * 32 + quad * 8);
#pragma unroll
      for (int dt = 0; dt < 4; ++dt) {
        half8 av = *(const half8*)(VTB + (dt * 16 + l15) * 72 + kc * 32 + quad * 8);
        o[dt] = __builtin_amdgcn_mfma_f32_16x16x32_f16(av, bp, o[dt], 0, 0, 0);
      }
    }
    __builtin_amdgcn_s_setprio(0);

    // stage tile i+1 into the other buffer; single lgkm-only barrier closes the iter
    if (more) {
      _Float16* Kn = &Ks[buf ^ 1][0];
      _Float16* Vn = &VT[buf ^ 1][0];
      *(half8*)(Kn + srow * 72 + scol) = krn;
      *(half8*)(Vn + srow * 72 + scol) = vrn;
      asm volatile("s_waitcnt lgkmcnt(0)\ns_barrier" ::: "memory");
#pragma unroll
      for (int mt = 0; mt < 4; ++mt) mk[mt] = mkn[mt];
    }
  }
  // epilogue: ctx[token][h*64+d], d = dt*16 + quad*4 + r
  {
    float inv = 1.0f / lrun;
    const size_t token = (size_t)(b * S + q0 + wave * 16 + l15);
#pragma unroll
    for (int dt = 0; dt < 4; ++dt) {
      half4_t hv = {(_Float16)(o[dt][0] * inv), (_Float16)(o[dt][1] * inv),
                    (_Float16)(o[dt][2] * inv), (_Float16)(o[dt][3] * inv)};
      *(half4_t*)(ctx + token * 1024 + h * 64 + dt * 16 + quad * 4) = hv;
    }
  }
}

extern "C" void kernel_launch(void* const* d_in, const int* in_sizes, int n_in,
                              void* d_out, int out_size, void* d_ws, size_t ws_size,
                              hipStream_t stream) {
  const float* hs = (const float*)d_in[0];
  const float* mask = (const float*)d_in[1];
  const float* Wq = (const float*)d_in[2];
  const float* Wk = (const float*)d_in[3];
  const float* Wv = (const float*)d_in[4];
  const float* Wo = (const float*)d_in[5];
  const float* rel = (const float*)d_in[6];
  float* out = (float*)d_out;

  // workspace layout (56 MB)
  char* ws = (char*)d_ws;
  _Float16* hsF = (_Float16*)(ws);                 // [4096,1024]   8 MB
  _Float16* wqkvT = (_Float16*)(ws + (8u << 20));  // [3072,1024]   6 MB
  _Float16* woT = (_Float16*)(ws + (14u << 20));   // [1024,1024]   2 MB
  _Float16* qkv = (_Float16*)(ws + (16u << 20));   // [4096,3072]  24 MB (V-part unused)
  _Float16* ctx = (_Float16*)(ws + (40u << 20));   // [4096,1024]   8 MB
  _Float16* vT = (_Float16*)(ws + (48u << 20));    // [2,16,64,2048] 8 MB

  // prep: hs convert + all 4 weight transposes in one dispatch
  k_prep<<<8192, 256, 0, stream>>>(hs, Wq, Wk, Wv, Wo, hsF, wqkvT, woT);

  // QKV projection fused with HALF the bias-output stream (even 64-col chunks);
  // V-range blocks write vT directly (transposed epilogue)
  k_gemm_qkv_bias<<<dim3(24, 32), 256, 0, stream>>>(hsF, wqkvT, qkv, vT, rel,
                                                    out + 4194304);
  // fused flash attention: 8 waves x 16 q-rows, 4 waves/SIMD + the other
  // half of the bias stream (odd 64-col chunks)
  k_attn<<<dim3(16, 16, 2), 512, 0, stream>>>(qkv, vT, mask, rel, ctx, out + 4194304);
  // output projection
  k_gemm_n64<<<dim3(16, 32), 256, 0, stream>>>(ctx, woT, out, 1024, 1024);
}

// Round 6
// 420.316 us; speedup vs baseline: 1.0065x; 1.0009x over previous
//
#include <hip/hip_runtime.h>
#include <cstdint>

#define AS1 __attribute__((address_space(1)))
#define AS3 __attribute__((address_space(3)))

typedef _Float16 half8 __attribute__((ext_vector_type(8)));
typedef _Float16 half4_t __attribute__((ext_vector_type(4)));
typedef float v4f __attribute__((ext_vector_type(4)));

__device__ __forceinline__ void async_ld16(const void* g, void* l) {
  __builtin_amdgcn_global_load_lds((const AS1 uint32_t*)g, (AS3 uint32_t*)l, 16, 0, 0);
}

// T5 relative-position bucket for delta = k - q (bidirectional, 32 buckets, max_dist 128).
__device__ __forceinline__ int t5_bucket(int delta) {
  int n = -delta;  // n = q - k
  int ret = 0;
  if (n < 0) { ret = 16; n = -n; }
  if (n < 8) return n + ret;
  if (n >= 91) return 15 + ret;
  if ((n & (n - 1)) == 0) {
    int l = 31 - __clz(n);
    int v = 2 + 2 * l;
    return (v > 15 ? 15 : v) + ret;
  }
  int v = 8 + (int)(logf((float)n * 0.125f) * (8.0f / logf(16.0f)));
  return (v > 15 ? 15 : v) + ret;
}

// ---------------- prep: hs fp32->fp16 (x<4096) + 4 weight transposes (x>=4096) --------
__global__ void k_prep(const float* __restrict__ hs, const float* __restrict__ Wq,
                       const float* __restrict__ Wk, const float* __restrict__ Wv,
                       const float* __restrict__ Wo, _Float16* __restrict__ hsF,
                       _Float16* __restrict__ wqkvT, _Float16* __restrict__ woT) {
  const int tid = threadIdx.x;
  if (blockIdx.x < 4096) {
    int t = blockIdx.x * 256 + tid;
    float4 f = ((const float4*)hs)[t];
    half4_t h = {(_Float16)f.x, (_Float16)f.y, (_Float16)f.z, (_Float16)f.w};
    ((half4_t*)hsF)[t] = h;
    return;
  }
  __shared__ float tile[32][33];
  const int idx = blockIdx.x - 4096;
  const int z = idx >> 10, rem = idx & 1023;
  const float* src = (z == 0) ? Wq : (z == 1) ? Wk : (z == 2) ? Wv : Wo;
  _Float16* dst = (z < 3) ? (wqkvT + ((size_t)z << 20)) : woT;
  const int tx = tid & 31, ty = tid >> 5;
  const int bx = (rem & 31) * 32, by = (rem >> 5) * 32;
#pragma unroll
  for (int i = 0; i < 32; i += 8)
    tile[ty + i][tx] = src[(size_t)(by + ty + i) * 1024 + bx + tx];
  __syncthreads();
#pragma unroll
  for (int i = 0; i < 32; i += 8)
    dst[(size_t)(bx + ty + i) * 1024 + by + tx] = (_Float16)tile[tx][ty + i];
}

// ---------------- QKV GEMM, true double-buffered LDS + bias writer (EVEN chunks) ------
// 128x128 tile, BK=32, grid (24,32) = 768 blocks = 3/CU. T3 minimum-2-phase:
// iter i issues stage(buf^1) at its TOP, computes on buf (confirmed complete at the END
// of iter i-1 via per-wave vmcnt), and closes with ONE barrier. The end-of-iter
// s_waitcnt vmcnt(2|0) waits on loads issued a full iteration of work earlier -> HBM
// staging latency is hidden (the old structure exposed ~500-900 cyc EVERY iteration:
// its barrier-2 vmcnt waited on loads issued ~20 instructions before). Bias stores are
// issued after the loads (sched_barrier keeps queue order L4,S2), so vmcnt(2) retires
// all loads while the 2 newest stores stay in flight across the barrier.
__global__ __launch_bounds__(256, 3) void k_gemm_qkv_bias(
    const _Float16* __restrict__ A, const _Float16* __restrict__ BT,
    _Float16* __restrict__ qkv, _Float16* __restrict__ vT,
    const float* __restrict__ rel, float* __restrict__ outb) {
  __shared__ __align__(16) _Float16 As[2][128 * 32];
  __shared__ __align__(16) _Float16 Bs[2][128 * 32];
  __shared__ float btab[256];  // bias vs delta in [-128,127] (mixed band only)
  const int tid = threadIdx.x;
  const int wave = tid >> 6, lane = tid & 63;
  const int l15 = lane & 15, quad = lane >> 4;
  const int m0 = blockIdx.y * 128, n0 = blockIdx.x * 128;
  const int wm = (wave >> 1) * 64, wn = (wave & 1) * 64;
  const int r0 = tid >> 2, c0 = (tid & 3) * 8;
  constexpr int K = 1024;

  const int bid = blockIdx.y * 24 + blockIdx.x;  // 0..767
  const bool do_bias = bid < 512;
  const int hB = bid >> 5;           // head for this block's bias slice
  const int qoff = (bid & 31) * 64;  // 64-q strip within the head
  float c_past = 0.f, c_fut = 0.f;
  if (do_bias) {
    btab[tid & 255] = rel[t5_bucket((tid & 255) - 128) * 16 + hB];
    c_past = rel[15 * 16 + hB];
    c_fut = rel[31 * 16 + hB];
  }

  // prologue: stage tile 0 into buf 0, drain, barrier (also publishes btab)
  async_ld16(A + (size_t)(m0 + r0) * K + c0, (char*)As[0] + (size_t)(wave * 64) * 16);
  async_ld16(A + (size_t)(m0 + 64 + r0) * K + c0,
             (char*)As[0] + (size_t)(256 + wave * 64) * 16);
  async_ld16(BT + (size_t)(n0 + r0) * K + c0, (char*)Bs[0] + (size_t)(wave * 64) * 16);
  async_ld16(BT + (size_t)(n0 + 64 + r0) * K + c0,
             (char*)Bs[0] + (size_t)(256 + wave * 64) * 16);
  asm volatile("s_waitcnt vmcnt(0) lgkmcnt(0)\ns_barrier" ::: "memory");

  v4f acc[4][4] = {};
  for (int iter = 0; iter < 32; ++iter) {
    const int buf = iter & 1;
    const int k0 = iter * 32;
    // stage tile iter+1 into buf^1 (safe: barrier at end of iter-1 means all waves
    // finished READING buf^1's previous contents)
    if (iter < 31) {
      const int kn = k0 + 32;
      async_ld16(A + (size_t)(m0 + r0) * K + kn + c0,
                 (char*)As[buf ^ 1] + (size_t)(wave * 64) * 16);
      async_ld16(A + (size_t)(m0 + 64 + r0) * K + kn + c0,
                 (char*)As[buf ^ 1] + (size_t)(256 + wave * 64) * 16);
      async_ld16(BT + (size_t)(n0 + r0) * K + kn + c0,
                 (char*)Bs[buf ^ 1] + (size_t)(wave * 64) * 16);
      async_ld16(BT + (size_t)(n0 + 64 + r0) * K + kn + c0,
                 (char*)Bs[buf ^ 1] + (size_t)(256 + wave * 64) * 16);
    }
    __builtin_amdgcn_sched_barrier(0);  // keep stage loads OLDER than bias stores

    if (do_bias) {
      // ---- bias strip (even 64-col chunks): 512 float4 (8 KB) per iter, coalesced ----
#pragma unroll
      for (int j = 0; j < 2; ++j) {
        int fi = iter * 512 + j * 256 + tid;       // 0..16383 within this block's slice
        int qr = qoff + (fi >> 8);                 // q row (2 rows per iter)
        int c = fi & 255;                          // float4 col in even-chunk space
        int k4 = ((c >> 4) << 5) + (c & 15);       // float4 col in full 512-wide row
        int kb = k4 << 2;                          // k element
        float4 v;
        if (kb - qr >= 91) {
          v = make_float4(c_fut, c_fut, c_fut, c_fut);
        } else if (qr - kb - 3 >= 91) {
          v = make_float4(c_past, c_past, c_past, c_past);
        } else {
          v.x = btab[kb + 0 - qr + 128];
          v.y = btab[kb + 1 - qr + 128];
          v.z = btab[kb + 2 - qr + 128];
          v.w = btab[kb + 3 - qr + 128];
        }
        ((float4*)outb)[((size_t)hB * 2048 + qr) * 512 + k4] = v;
      }
    }

    // compute on buf (its 4 staging loads were confirmed retired at end of iter-1)
    half8 af[4], bf[4];
#pragma unroll
    for (int mt = 0; mt < 4; ++mt)
      af[mt] = *(const half8*)(&As[buf][(wm + mt * 16 + l15) * 32 + quad * 8]);
#pragma unroll
    for (int nt = 0; nt < 4; ++nt)
      bf[nt] = *(const half8*)(&Bs[buf][(wn + nt * 16 + l15) * 32 + quad * 8]);
#pragma unroll
    for (int mt = 0; mt < 4; ++mt)
#pragma unroll
      for (int nt = 0; nt < 4; ++nt)
        acc[mt][nt] = __builtin_amdgcn_mfma_f32_16x16x32_f16(af[mt], bf[nt], acc[mt][nt], 0, 0, 0);

    // end of iter: retire THIS iter's 4 staging loads (issued a full iteration of
    // work ago); bias blocks keep their 2 newest stores in flight. One barrier.
    if (do_bias) {
      asm volatile("s_waitcnt vmcnt(2)\ns_barrier" ::: "memory");
    } else {
      asm volatile("s_waitcnt vmcnt(0)\ns_barrier" ::: "memory");
    }
  }

  if (n0 >= 2048) {
    // V block: write vT[((b*16+h)*64+d)][s], 4 consecutive s per lane -> b64 stores
#pragma unroll
    for (int mt = 0; mt < 4; ++mt)
#pragma unroll
      for (int nt = 0; nt < 4; ++nt) {
        int col = n0 + wn + nt * 16 + l15 - 2048;  // h*64 + d
        int row0 = m0 + wm + mt * 16 + quad * 4;   // token
        int bb = row0 >> 11, s0 = row0 & 2047;
        half4_t hv = {(_Float16)acc[mt][nt][0], (_Float16)acc[mt][nt][1],
                      (_Float16)acc[mt][nt][2], (_Float16)acc[mt][nt][3]};
        *(half4_t*)(vT + ((size_t)bb * 1024 + col) * 2048 + s0) = hv;
      }
    return;
  }
#pragma unroll
  for (int mt = 0; mt < 4; ++mt)
#pragma unroll
    for (int nt = 0; nt < 4; ++nt)
#pragma unroll
      for (int r = 0; r < 4; ++r)
        qkv[(size_t)(m0 + wm + mt * 16 + quad * 4 + r) * 3072 + n0 + wn + nt * 16 + l15] =
            (_Float16)acc[mt][nt][r];
}

// ---------------- output projection GEMM: 128x64 tile, double-buffered ----------------
__global__ __launch_bounds__(256, 2) void k_gemm_n64(const _Float16* __restrict__ A,
                                                     const _Float16* __restrict__ BT,
                                                     float* __restrict__ C, int K, int ldc) {
  __shared__ __align__(16) _Float16 As[2][128 * 32];
  __shared__ __align__(16) _Float16 Bs[2][64 * 32];
  const int tid = threadIdx.x;
  const int wave = tid >> 6, lane = tid & 63;
  const int l15 = lane & 15, quad = lane >> 4;
  const int m0 = blockIdx.y * 128, n0 = blockIdx.x * 64;
  const int wm = (wave >> 1) * 64, wn = (wave & 1) * 32;
  const int r0 = tid >> 2, c0 = (tid & 3) * 8;

  async_ld16(A + (size_t)(m0 + r0) * K + c0, (char*)As[0] + (size_t)(wave * 64) * 16);
  async_ld16(A + (size_t)(m0 + 64 + r0) * K + c0,
             (char*)As[0] + (size_t)(256 + wave * 64) * 16);
  async_ld16(BT + (size_t)(n0 + r0) * K + c0, (char*)Bs[0] + (size_t)(wave * 64) * 16);
  asm volatile("s_waitcnt vmcnt(0) lgkmcnt(0)\ns_barrier" ::: "memory");

  v4f acc[4][2] = {};
  const int iters = K >> 5;
  for (int iter = 0; iter < iters; ++iter) {
    const int buf = iter & 1;
    if (iter < iters - 1) {
      const int kn = iter * 32 + 32;
      async_ld16(A + (size_t)(m0 + r0) * K + kn + c0,
                 (char*)As[buf ^ 1] + (size_t)(wave * 64) * 16);
      async_ld16(A + (size_t)(m0 + 64 + r0) * K + kn + c0,
                 (char*)As[buf ^ 1] + (size_t)(256 + wave * 64) * 16);
      async_ld16(BT + (size_t)(n0 + r0) * K + kn + c0,
                 (char*)Bs[buf ^ 1] + (size_t)(wave * 64) * 16);
    }
    half8 af[4], bf[2];
#pragma unroll
    for (int mt = 0; mt < 4; ++mt)
      af[mt] = *(const half8*)(&As[buf][(wm + mt * 16 + l15) * 32 + quad * 8]);
#pragma unroll
    for (int nt = 0; nt < 2; ++nt)
      bf[nt] = *(const half8*)(&Bs[buf][(wn + nt * 16 + l15) * 32 + quad * 8]);
#pragma unroll
    for (int mt = 0; mt < 4; ++mt)
#pragma unroll
      for (int nt = 0; nt < 2; ++nt)
        acc[mt][nt] = __builtin_amdgcn_mfma_f32_16x16x32_f16(af[mt], bf[nt], acc[mt][nt], 0, 0, 0);
    asm volatile("s_waitcnt vmcnt(0)\ns_barrier" ::: "memory");
  }
#pragma unroll
  for (int mt = 0; mt < 4; ++mt)
#pragma unroll
    for (int nt = 0; nt < 2; ++nt)
#pragma unroll
      for (int r = 0; r < 4; ++r)
        C[(size_t)(m0 + wm + mt * 16 + quad * 4 + r) * ldc + n0 + wn + nt * 16 + l15] =
            acc[mt][nt][r];
}

// ---------------- fused flash attention: 8 waves x 16 q-rows, 4 waves/SIMD -----------
// (unchanged from the passing R4 version)
__global__ __launch_bounds__(512, 4) void k_attn(const _Float16* __restrict__ qkv,
                                                 const _Float16* __restrict__ vT,
                                                 const float* __restrict__ mask,
                                                 const float* __restrict__ rel,
                                                 _Float16* __restrict__ ctx,
                                                 float* __restrict__ outb) {
  constexpr int S = 2048, LD = 3072;
  __shared__ __align__(16) _Float16 Ks[2][64 * 72];  // [buf][kv][d] pad->LD 72
  __shared__ __align__(16) _Float16 VT[2][64 * 72];  // [buf][d][kv]
  __shared__ __align__(16) _Float16 Psh[128 * 72];   // [q][kv] per-wave-owned rows
  __shared__ float btab[512];                        // bias vs delta in [-256,255]
  const int tid = threadIdx.x, wave = tid >> 6, lane = tid & 63;
  const int l15 = lane & 15, quad = lane >> 4;
  // XCD-aware chunked remap of the 512-block grid (bijective since 512 % 8 == 0)
  const int flat = blockIdx.x + 16 * (blockIdx.y + 16 * blockIdx.z);
  const int swz = (flat & 7) * 64 + (flat >> 3);
  const int q0 = (swz & 15) * 128, h = (swz >> 4) & 15, b = swz >> 8;

  btab[tid] = rel[t5_bucket((int)tid - 256) * 16 + h];
  const float c_past = rel[15 * 16 + h];  // q - k >= 91
  const float c_fut = rel[31 * 16 + h];   // k - q >= 91

  // wave owns q rows [q0 + wave*16, q0 + wave*16 + 16)
  half8 bq[2];
  {
    const _Float16* qp = qkv + (size_t)(b * S + q0 + wave * 16 + l15) * LD + h * 64;
    bq[0] = *(const half8*)(qp + quad * 8);
    bq[1] = *(const half8*)(qp + 32 + quad * 8);
  }
  v4f o[4] = {};
  float mrun = -INFINITY;
  float lrun = 0.f;

  // staging shard: 512 threads cover the 64x64 tile with one half8 each
  const int srow = tid >> 3, scol = (tid & 7) * 8;
  const _Float16* kg = qkv + (size_t)(b * S + srow) * LD + 1024 + h * 64 + scol;
  const _Float16* vg = vT + ((size_t)((b * 16 + h) * 64 + srow)) * S + scol;
  const float4* mkp = (const float4*)(mask + (size_t)b * S);

  // bias-writer constants: this block owns q-rows [qrow0, qrow0+64) of head h
  const int qrow0 = q0 + b * 64;
  float4* const bias_base = (float4*)outb + ((size_t)h * 2048 + qrow0) * 512;

  // stage tile 0 into buf 0
  {
    half8 kr = *(const half8*)(kg);
    half8 vr = *(const half8*)(vg);
    *(half8*)(&Ks[0][srow * 72 + scol]) = kr;
    *(half8*)(&VT[0][srow * 72 + scol]) = vr;
  }
  float4 mk[4];
#pragma unroll
  for (int mt = 0; mt < 4; ++mt) mk[mt] = mkp[mt * 4 + quad];
  __syncthreads();  // tile0 + btab visible

  for (int kv0 = 0; kv0 < S; kv0 += 64) {
    const int buf = (kv0 >> 6) & 1;
    const bool more = (kv0 + 64) < S;
    // prefetch tile i+1 globals (consumed after compute)
    half8 krn, vrn;
    float4 mkn[4];
    if (more) {
      krn = *(const half8*)(kg + (size_t)(kv0 + 64) * LD);
      vrn = *(const half8*)(vg + kv0 + 64);
#pragma unroll
      for (int mt = 0; mt < 4; ++mt) mkn[mt] = mkp[((kv0 + 64) >> 2) + mt * 4 + quad];
    }

    // ---- position-bias stream: odd 64-col chunks, 64 q-rows x 64 k per store-iter ----
    if (kv0 & 64) {
      const int diffw = kv0 - qrow0;
      float4* dst = bias_base + (kv0 >> 2);
      if (diffw >= 154) {
        const float4 v = make_float4(c_fut, c_fut, c_fut, c_fut);
#pragma unroll
        for (int j = 0; j < 2; ++j) {
          int fi = j * 512 + tid;
          dst[(size_t)(fi >> 4) * 512 + (fi & 15)] = v;
        }
      } else if (diffw <= -154) {
        const float4 v = make_float4(c_past, c_past, c_past, c_past);
#pragma unroll
        for (int j = 0; j < 2; ++j) {
          int fi = j * 512 + tid;
          dst[(size_t)(fi >> 4) * 512 + (fi & 15)] = v;
        }
      } else {  // mixed tile: |delta| <= 216 -> btab[delta+256] in range
#pragma unroll
        for (int j = 0; j < 2; ++j) {
          int fi = j * 512 + tid;
          int row = fi >> 4, c4 = fi & 15;
          int q = qrow0 + row, k = kv0 + c4 * 4;
          float4 v;
          if (k - q >= 91) {
            v = make_float4(c_fut, c_fut, c_fut, c_fut);
          } else if (q - k - 3 >= 91) {
            v = make_float4(c_past, c_past, c_past, c_past);
          } else {
            int bi = k - q + 256;
            v.x = btab[bi + 0];
            v.y = btab[bi + 1];
            v.z = btab[bi + 2];
            v.w = btab[bi + 3];
          }
          dst[(size_t)row * 512 + c4] = v;
        }
      }
    }

    // S^T: sc[mt][r] = score(kv = kv0+mt*16+quad*4+r, q = q0+wave*16+l15)
    const _Float16* KsB = &Ks[buf][0];
    const _Float16* VTB = &VT[buf][0];
    v4f sc[4] = {};
    __builtin_amdgcn_s_setprio(1);
#pragma unroll
    for (int kc = 0; kc < 2; ++kc)
#pragma unroll
      for (int mt = 0; mt < 4; ++mt) {
        half8 af = *(const half8*)(KsB + (mt * 16 + l15) * 72 + kc * 32 + quad * 8);
        sc[mt] = __builtin_amdgcn_mfma_f32_16x16x32_f16(af, bq[kc], sc[mt], 0, 0, 0);
      }
    __builtin_amdgcn_s_setprio(0);

    // bias + mask; block-uniform tile classification (mixed deltas fit btab[512])
    const int diff = kv0 - q0;
    const bool mixed = (diff >= -153) && (diff <= 217);
    const float cf = (diff >= 218) ? c_fut : c_past;
    v4f cm[4];
#pragma unroll
    for (int mt = 0; mt < 4; ++mt) {
      cm[mt][0] = mk[mt].x; cm[mt][1] = mk[mt].y; cm[mt][2] = mk[mt].z; cm[mt][3] = mk[mt].w;
      if (!mixed) {
        cm[mt][0] += cf; cm[mt][1] += cf; cm[mt][2] += cf; cm[mt][3] += cf;
      }
    }
    if (mixed) {
      const int qq = q0 + wave * 16 + l15;
#pragma unroll
      for (int mt = 0; mt < 4; ++mt) {
        int base = kv0 + mt * 16 + quad * 4 - qq + 256;
#pragma unroll
        for (int r = 0; r < 4; ++r) sc[mt][r] += btab[base + r] + cm[mt][r];
      }
    } else {
#pragma unroll
      for (int mt = 0; mt < 4; ++mt)
#pragma unroll
        for (int r = 0; r < 4; ++r) sc[mt][r] += cm[mt][r];
    }

    // online softmax (one q per lane; reduce across quads: xor 16, 32)
    {
      v4f m4 = sc[0];
#pragma unroll
      for (int r = 0; r < 4; ++r) {
        m4[r] = fmaxf(m4[r], sc[1][r]);
        m4[r] = fmaxf(m4[r], sc[2][r]);
        m4[r] = fmaxf(m4[r], sc[3][r]);
      }
      float mx = fmaxf(fmaxf(m4[0], m4[1]), fmaxf(m4[2], m4[3]));
      mx = fmaxf(mx, __shfl_xor(mx, 16, 64));
      mx = fmaxf(mx, __shfl_xor(mx, 32, 64));
      // exact defer-max: if no lane grew, alpha == 1 for every lane -> skip rescale
      if (!__all(mx <= mrun)) {
        float mnew = fmaxf(mrun, mx);
        float alpha = __expf(mrun - mnew);
        mrun = mnew;
        lrun *= alpha;
#pragma unroll
        for (int dt = 0; dt < 4; ++dt)
#pragma unroll
          for (int r = 0; r < 4; ++r) o[dt][r] *= alpha;
      }
      const float mcur = mrun;
      v4f s4 = {};
#pragma unroll
      for (int mt = 0; mt < 4; ++mt)
#pragma unroll
        for (int r = 0; r < 4; ++r) {
          float p = __expf(sc[mt][r] - mcur);
          sc[mt][r] = p;
          s4[r] += p;
        }
      float rs = (s4[0] + s4[1]) + (s4[2] + s4[3]);
      rs += __shfl_xor(rs, 16, 64);
      rs += __shfl_xor(rs, 32, 64);
      lrun += rs;
      // P write: 4 consecutive kv per lane -> packed b64 (own-wave rows only)
      const int prow = wave * 16 + l15;
#pragma unroll
      for (int mt = 0; mt < 4; ++mt) {
        half4_t ph = {(_Float16)sc[mt][0], (_Float16)sc[mt][1],
                      (_Float16)sc[mt][2], (_Float16)sc[mt][3]};
        *(half4_t*)(Psh + prow * 72 + mt * 16 + quad * 4) = ph;
      }
    }
    // NO barrier: PV reads only this wave's own P rows (same-wave LDS RAW -> lgkmcnt)

    // O^T += V^T * P^T
    __builtin_amdgcn_s_setprio(1);
#pragma unroll
    for (int kc = 0; kc < 2; ++kc) {
      half8 bp = *(const half8*)(Psh + (wave * 16 + l15) * 72 + kc * 32 + quad * 8);
#pragma unroll
      for (int dt = 0; dt < 4; ++dt) {
        half8 av = *(const half8*)(VTB + (dt * 16 + l15) * 72 + kc * 32 + quad * 8);
        o[dt] = __builtin_amdgcn_mfma_f32_16x16x32_f16(av, bp, o[dt], 0, 0, 0);
      }
    }
    __builtin_amdgcn_s_setprio(0);

    // stage tile i+1 into the other buffer; single lgkm-only barrier closes the iter
    if (more) {
      _Float16* Kn = &Ks[buf ^ 1][0];
      _Float16* Vn = &VT[buf ^ 1][0];
      *(half8*)(Kn + srow * 72 + scol) = krn;
      *(half8*)(Vn + srow * 72 + scol) = vrn;
      asm volatile("s_waitcnt lgkmcnt(0)\ns_barrier" ::: "memory");
#pragma unroll
      for (int mt = 0; mt < 4; ++mt) mk[mt] = mkn[mt];
    }
  }
  // epilogue: ctx[token][h*64+d], d = dt*16 + quad*4 + r
  {
    float inv = 1.0f / lrun;
    const size_t token = (size_t)(b * S + q0 + wave * 16 + l15);
#pragma unroll
    for (int dt = 0; dt < 4; ++dt) {
      half4_t hv = {(_Float16)(o[dt][0] * inv), (_Float16)(o[dt][1] * inv),
                    (_Float16)(o[dt][2] * inv), (_Float16)(o[dt][3] * inv)};
      *(half4_t*)(ctx + token * 1024 + h * 64 + dt * 16 + quad * 4) = hv;
    }
  }
}

extern "C" void kernel_launch(void* const* d_in, const int* in_sizes, int n_in,
                              void* d_out, int out_size, void* d_ws, size_t ws_size,
                              hipStream_t stream) {
  const float* hs = (const float*)d_in[0];
  const float* mask = (const float*)d_in[1];
  const float* Wq = (const float*)d_in[2];
  const float* Wk = (const float*)d_in[3];
  const float* Wv = (const float*)d_in[4];
  const float* Wo = (const float*)d_in[5];
  const float* rel = (const float*)d_in[6];
  float* out = (float*)d_out;

  // workspace layout (56 MB)
  char* ws = (char*)d_ws;
  _Float16* hsF = (_Float16*)(ws);                 // [4096,1024]   8 MB
  _Float16* wqkvT = (_Float16*)(ws + (8u << 20));  // [3072,1024]   6 MB
  _Float16* woT = (_Float16*)(ws + (14u << 20));   // [1024,1024]   2 MB
  _Float16* qkv = (_Float16*)(ws + (16u << 20));   // [4096,3072]  24 MB (V-part unused)
  _Float16* ctx = (_Float16*)(ws + (40u << 20));   // [4096,1024]   8 MB
  _Float16* vT = (_Float16*)(ws + (48u << 20));    // [2,16,64,2048] 8 MB

  // prep: hs convert + all 4 weight transposes in one dispatch
  k_prep<<<8192, 256, 0, stream>>>(hs, Wq, Wk, Wv, Wo, hsF, wqkvT, woT);

  // QKV projection (double-buffered) fused with HALF the bias-output stream;
  // V-range blocks write vT directly (transposed epilogue)
  k_gemm_qkv_bias<<<dim3(24, 32), 256, 0, stream>>>(hsF, wqkvT, qkv, vT, rel,
                                                    out + 4194304);
  // fused flash attention: 8 waves x 16 q-rows, 4 waves/SIMD + the other
  // half of the bias stream (odd 64-col chunks)
  k_attn<<<dim3(16, 16, 2), 512, 0, stream>>>(qkv, vT, mask, rel, ctx, out + 4194304);
  // output projection (double-buffered)
  k_gemm_n64<<<dim3(16, 32), 256, 0, stream>>>(ctx, woT, out, 1024, 1024);
}